// Round 4
// baseline (928.307 us; speedup 1.0000x reference)
//
#include <hip/hip_runtime.h>
#include <math.h>

#define B_    4
#define CIN_  32
#define COUT_ 64
#define H_    192
#define W_    192
#define HW_   (H_ * W_)        // 36864
#define NPIX_ (B_ * HW_)       // 147456
#define EPS_  1e-5f

// ---------------------------------------------------------------------------
// Kernel 0a: transpose x (NCHW) -> xt (NHWC: [b][h][w][32]).
// Reads coalesced per channel; each thread writes its pixel's 128 B.
// ---------------------------------------------------------------------------
__global__ __launch_bounds__(256) void k_tr(
    const float* __restrict__ x, float* __restrict__ xt)
{
    const int pid = blockIdx.x * 256 + threadIdx.x;   // pixel id < NPIX_
    const int b   = pid / HW_;
    const int rem = pid - b * HW_;
    const float* xb = x + (size_t)b * CIN_ * HW_ + rem;
    float4 v[8];
#pragma unroll
    for (int j = 0; j < 8; ++j) {
        v[j].x = xb[(j * 4 + 0) * HW_];
        v[j].y = xb[(j * 4 + 1) * HW_];
        v[j].z = xb[(j * 4 + 2) * HW_];
        v[j].w = xb[(j * 4 + 3) * HW_];
    }
    float4* dst = (float4*)(xt + (size_t)pid * 32);
#pragma unroll
    for (int j = 0; j < 8; ++j) dst[j] = v[j];
}

// ---------------------------------------------------------------------------
// Kernel 0b: weight transposes + stats zeroing (as round 3).
// wt_def[kk][c][64], wt_off[kk][c][20] (padded), stats zeroed.
// ---------------------------------------------------------------------------
__global__ __launch_bounds__(256) void k_prep(
    const float* __restrict__ w_def, const float* __restrict__ w_off,
    float* __restrict__ wt_def, float* __restrict__ wt_off,
    float* __restrict__ stats)
{
    const int i = blockIdx.x * 256 + threadIdx.x;
    if (i < 18432) {
        const int o  = i & 63;
        const int c  = (i >> 6) & 31;
        const int kk = i >> 11;
        wt_def[i] = w_def[(o * 32 + c) * 9 + kk];
    } else if (i < 18432 + 5760) {
        const int e  = i - 18432;
        const int o  = e % 20;
        const int t  = e / 20;
        const int c  = t & 31;
        const int kk = t >> 5;
        wt_off[e] = (o < 18) ? w_off[(o * 32 + c) * 9 + kk] : 0.f;
    } else if (i < 18432 + 5760 + 512) {
        stats[i - 18432 - 5760] = 0.f;
    }
}

// ---------------------------------------------------------------------------
// Kernel 1: offsets conv (32 -> 18 ch), NHWC input, kk-level prefetch.
// ---------------------------------------------------------------------------
__global__ __launch_bounds__(256) void k_conv_off(
    const float* __restrict__ xt, const float* __restrict__ wt,
    const float* __restrict__ b_off, float* __restrict__ offs)
{
    const int pid = blockIdx.x * 256 + threadIdx.x;
    const int b   = pid / HW_;
    const int rem = pid - b * HW_;
    const int h   = rem / W_;
    const int w   = rem - h * W_;
    const float* xb = xt + (size_t)b * HW_ * 32;

    float acc[20];
#pragma unroll
    for (int o = 0; o < 20; ++o) acc[o] = 0.f;

    auto tap = [&](int kk, const float4*& p, float& gate) {
        const int yy = h + kk / 3 - 1;
        const int sx = w + kk % 3 - 1;
        const bool ok = (yy >= 0) & (yy < H_) & (sx >= 0) & (sx < W_);
        const int cy = min(max(yy, 0), H_ - 1);
        const int cx = min(max(sx, 0), W_ - 1);
        p = (const float4*)(xb + (cy * W_ + cx) * 32);
        gate = ok ? 1.f : 0.f;
    };

    const float4* p; float g;
    tap(0, p, g);
    float4 cur[8];
#pragma unroll
    for (int j = 0; j < 8; ++j) cur[j] = p[j];

#pragma unroll 1
    for (int kk = 0; kk < 9; ++kk) {
        float4 nxt[8];
        const float4* np; float ng = 0.f;
        if (kk < 8) {
            tap(kk + 1, np, ng);
#pragma unroll
            for (int j = 0; j < 8; ++j) nxt[j] = np[j];
        }
        const float gg = g;
#pragma unroll
        for (int j = 0; j < 8; ++j) {
            const float4 xv = cur[j];
            const float vs[4] = {xv.x * gg, xv.y * gg, xv.z * gg, xv.w * gg};
#pragma unroll
            for (int e = 0; e < 4; ++e) {
                const int c = j * 4 + e;
                const float4* wr = (const float4*)(wt + (kk * 32 + c) * 20);
                const float a = vs[e];
#pragma unroll
                for (int q = 0; q < 5; ++q) {
                    float4 wv = wr[q];
                    acc[q * 4 + 0] += a * wv.x;
                    acc[q * 4 + 1] += a * wv.y;
                    acc[q * 4 + 2] += a * wv.z;
                    acc[q * 4 + 3] += a * wv.w;
                }
            }
        }
        if (kk < 8) {
            g = ng;
#pragma unroll
            for (int j = 0; j < 8; ++j) cur[j] = nxt[j];
        }
    }

#pragma unroll
    for (int o = 0; o < 18; ++o)
        offs[(b * 18 + o) * HW_ + rem] = acc[o] + b_off[o];
}

// ---------------------------------------------------------------------------
// Kernel 2: deformable conv, NHWC gathers, 8-channel chunks with A/B
// double-buffered prefetch; weights via uniform (scalar) loads.
// ---------------------------------------------------------------------------
struct Cr { const float4 *q00, *q01, *q10, *q11; float w00, w01, w10, w11; };

__global__ __launch_bounds__(256, 2) void k_deform(
    const float* __restrict__ xt, const float* __restrict__ offs,
    const float* __restrict__ wt, const float* __restrict__ b_def,
    float* __restrict__ y)
{
    const int pid = blockIdx.x * 256 + threadIdx.x;
    const int b   = pid / HW_;
    const int rem = pid - b * HW_;
    const int h   = rem / W_;
    const int w   = rem - h * W_;
    const float* xb = xt + (size_t)b * HW_ * 32;
    const float* ob = offs + b * 18 * HW_ + rem;

    // preload all 18 offset values (loads fully overlapped)
    float dyv[9], dxv[9];
#pragma unroll
    for (int kk = 0; kk < 9; ++kk) {
        dyv[kk] = ob[(2 * kk) * HW_];
        dxv[kk] = ob[(2 * kk + 1) * HW_];
    }

    float acc[64];
#pragma unroll
    for (int o = 0; o < 64; ++o) acc[o] = 0.f;

    auto mk = [&](int kk) -> Cr {
        const float py = (float)(h + kk / 3 - 1) + dyv[kk];
        const float px = (float)(w + kk % 3 - 1) + dxv[kk];
        const float y0f = floorf(py), x0f = floorf(px);
        const float wy = py - y0f, wx = px - x0f;
        const int iy0 = (int)y0f, ix0 = (int)x0f;
        const int iy1 = iy0 + 1,  ix1 = ix0 + 1;
        const float vy0 = (iy0 >= 0 && iy0 < H_) ? 1.f : 0.f;
        const float vy1 = (iy1 >= 0 && iy1 < H_) ? 1.f : 0.f;
        const float vx0 = (ix0 >= 0 && ix0 < W_) ? 1.f : 0.f;
        const float vx1 = (ix1 >= 0 && ix1 < W_) ? 1.f : 0.f;
        Cr c;
        c.w00 = (1.f - wy) * (1.f - wx) * vy0 * vx0;
        c.w01 = (1.f - wy) * wx * vy0 * vx1;
        c.w10 = wy * (1.f - wx) * vy1 * vx0;
        c.w11 = wy * wx * vy1 * vx1;
        const int cy0 = min(max(iy0, 0), H_ - 1), cy1 = min(max(iy1, 0), H_ - 1);
        const int cx0 = min(max(ix0, 0), W_ - 1), cx1 = min(max(ix1, 0), W_ - 1);
        c.q00 = (const float4*)(xb + (cy0 * W_ + cx0) * 32);
        c.q01 = (const float4*)(xb + (cy0 * W_ + cx1) * 32);
        c.q10 = (const float4*)(xb + (cy1 * W_ + cx0) * 32);
        c.q11 = (const float4*)(xb + (cy1 * W_ + cx1) * 32);
        return c;
    };

    // chunk = 8 channels: 2 float4 from each of the 4 corners
    auto loadc = [&](const Cr& c, int j0, float4* buf) {
#pragma unroll
        for (int j = 0; j < 2; ++j) {
            buf[0 + j] = c.q00[j0 + j];
            buf[2 + j] = c.q01[j0 + j];
            buf[4 + j] = c.q10[j0 + j];
            buf[6 + j] = c.q11[j0 + j];
        }
    };
    auto vburst = [&](const Cr& c, int kk, int c0, const float4* buf) {
        float v[8];
#pragma unroll
        for (int j = 0; j < 2; ++j) {
            const float4 a = buf[0 + j], bq = buf[2 + j];
            const float4 cc = buf[4 + j], d = buf[6 + j];
            v[j * 4 + 0] = c.w00 * a.x + c.w01 * bq.x + c.w10 * cc.x + c.w11 * d.x;
            v[j * 4 + 1] = c.w00 * a.y + c.w01 * bq.y + c.w10 * cc.y + c.w11 * d.y;
            v[j * 4 + 2] = c.w00 * a.z + c.w01 * bq.z + c.w10 * cc.z + c.w11 * d.z;
            v[j * 4 + 3] = c.w00 * a.w + c.w01 * bq.w + c.w10 * cc.w + c.w11 * d.w;
        }
#pragma unroll
        for (int e = 0; e < 8; ++e) {
            const float vc = v[e];
            const float4* wr = (const float4*)(wt + ((kk * 32 + c0 + e) << 6));
#pragma unroll
            for (int q = 0; q < 16; ++q) {
                float4 wv = wr[q];
                acc[q * 4 + 0] += vc * wv.x;
                acc[q * 4 + 1] += vc * wv.y;
                acc[q * 4 + 2] += vc * wv.z;
                acc[q * 4 + 3] += vc * wv.w;
            }
        }
    };

    Cr cur = mk(0);
    float4 A[8], Bv[8];
    loadc(cur, 0, A);                       // chunk (kk=0, c0=0)
#pragma unroll 1
    for (int kk = 0; kk < 9; ++kk) {
        loadc(cur, 2, Bv);                  // prefetch c0=8
        vburst(cur, kk, 0, A);
        loadc(cur, 4, A);                   // prefetch c0=16
        vburst(cur, kk, 8, Bv);
        loadc(cur, 6, Bv);                  // prefetch c0=24
        vburst(cur, kk, 16, A);
        Cr nx = (kk < 8) ? mk(kk + 1) : cur;
        if (kk < 8) loadc(nx, 0, A);        // prefetch next kk's c0=0
        vburst(cur, kk, 24, Bv);
        cur = nx;
    }

    float* yp = y + (size_t)b * COUT_ * HW_ + rem;
#pragma unroll
    for (int o = 0; o < 64; ++o) yp[o * HW_] = acc[o] + b_def[o];
}

// ---------------------------------------------------------------------------
// Kernel 3: per-(b,c) sum / sum-of-squares of y (NCHW planes), float4 loads.
// ---------------------------------------------------------------------------
__global__ __launch_bounds__(256) void k_stats(
    const float* __restrict__ y,
    float* __restrict__ sum_bc, float* __restrict__ sumsq_bc)
{
    const int i = blockIdx.x * 256 + threadIdx.x;
    const float4 v = ((const float4*)y)[i];
    float s = v.x + v.y + v.z + v.w;
    float q = v.x * v.x + v.y * v.y + v.z * v.z + v.w * v.w;
#pragma unroll
    for (int off = 32; off; off >>= 1) {
        s += __shfl_xor(s, off, 64);
        q += __shfl_xor(q, off, 64);
    }
    __shared__ float ls[4], lq[4];
    const int lane = threadIdx.x & 63, wid = threadIdx.x >> 6;
    if (lane == 0) { ls[wid] = s; lq[wid] = q; }
    __syncthreads();
    if (threadIdx.x == 0) {
        const float ts = ls[0] + ls[1] + ls[2] + ls[3];
        const float tq = lq[0] + lq[1] + lq[2] + lq[3];
        const int bc = (i * 4) / HW_;   // uniform within block
        atomicAdd(&sum_bc[bc], ts);
        atomicAdd(&sumsq_bc[bc], tq);
    }
}

// ---------------------------------------------------------------------------
// Kernel 4 (1 block): BN stats + SE MLP -> per-(b,c) affine alpha/bbias.
// ---------------------------------------------------------------------------
__global__ __launch_bounds__(256) void k_se(
    const float* __restrict__ sum_bc, const float* __restrict__ sumsq_bc,
    const float* __restrict__ gamma, const float* __restrict__ beta,
    const float* __restrict__ fc1_w, const float* __restrict__ fc1_b,
    const float* __restrict__ fc2_w, const float* __restrict__ fc2_b,
    float* __restrict__ alpha, float* __restrict__ bbias)
{
    const int tid = threadIdx.x;
    const int b = tid >> 6, c = tid & 63;

    float ch_s = 0.f, ch_q = 0.f;
#pragma unroll
    for (int bb = 0; bb < 4; ++bb) {
        ch_s += sum_bc[bb * 64 + c];
        ch_q += sumsq_bc[bb * 64 + c];
    }
    const float invN = 1.f / (float)(B_ * HW_);
    const float mean = ch_s * invN;
    const float var  = ch_q * invN - mean * mean;
    const float a    = gamma[c] * rsqrtf(var + EPS_);
    const float bi   = beta[c] - mean * a;

    __shared__ float sin_[256];
    sin_[tid] = a * (sum_bc[tid] * (1.f / (float)HW_)) + bi;
    __syncthreads();

    float hv[4];
#pragma unroll
    for (int j = 0; j < 4; ++j) {
        float hs = fc1_b[j];
        for (int cc = 0; cc < 64; ++cc) hs += sin_[b * 64 + cc] * fc1_w[j * 64 + cc];
        hv[j] = fmaxf(hs, 0.f);
    }
    float o = fc2_b[c];
#pragma unroll
    for (int j = 0; j < 4; ++j) o += hv[j] * fc2_w[c * 4 + j];
    const float s = 1.f / (1.f + expf(-o));

    alpha[tid] = a * s;
    bbias[tid] = bi * s;
}

// ---------------------------------------------------------------------------
// Kernel 5: fused affine(BN*SE) + ReLU + 2x2 maxpool -> out (4,64,96,96).
// ---------------------------------------------------------------------------
__global__ __launch_bounds__(256) void k_finish(
    const float* __restrict__ y,
    const float* __restrict__ alpha, const float* __restrict__ bbias,
    float* __restrict__ out)
{
    const int t    = blockIdx.x * 256 + threadIdx.x;
    const int opix = t * 2;
    const int bc   = opix / (96 * 96);
    const int rem  = opix - bc * (96 * 96);
    const int oh   = rem / 96, ow = rem - oh * 96;
    const float al = alpha[bc], bb = bbias[bc];
    const float* yp = y + (size_t)bc * HW_ + (2 * oh) * W_ + 2 * ow;
    const float4 r0 = *(const float4*)yp;
    const float4 r1 = *(const float4*)(yp + W_);
    float2 st;
    st.x = fmaxf(fmaxf(fmaxf(fmaf(r0.x, al, bb), fmaf(r0.y, al, bb)),
                       fmaxf(fmaf(r1.x, al, bb), fmaf(r1.y, al, bb))), 0.f);
    st.y = fmaxf(fmaxf(fmaxf(fmaf(r0.z, al, bb), fmaf(r0.w, al, bb)),
                       fmaxf(fmaf(r1.z, al, bb), fmaf(r1.w, al, bb))), 0.f);
    *(float2*)(out + opix) = st;
}

// ---------------------------------------------------------------------------
extern "C" void kernel_launch(void* const* d_in, const int* in_sizes, int n_in,
                              void* d_out, int out_size, void* d_ws, size_t ws_size,
                              hipStream_t stream)
{
    const float* x     = (const float*)d_in[0];
    const float* w_off = (const float*)d_in[1];
    const float* b_off = (const float*)d_in[2];
    const float* w_def = (const float*)d_in[3];
    const float* b_def = (const float*)d_in[4];
    const float* gamma = (const float*)d_in[5];
    const float* beta  = (const float*)d_in[6];
    const float* fc1_w = (const float*)d_in[7];
    const float* fc1_b = (const float*)d_in[8];
    const float* fc2_w = (const float*)d_in[9];
    const float* fc2_b = (const float*)d_in[10];
    float* out = (float*)d_out;

    float* ws   = (float*)d_ws;
    float* offs   = ws;                          // 2,654,208 floats
    float* yb     = offs + 2654208;              // 9,437,184 floats
    float* xt     = yb + 9437184;                // 4,718,592 floats (NHWC x)
    float* wt_def = xt + 4718592;                // 18,432
    float* wt_off = wt_def + 18432;              // 5,760
    float* stats  = wt_off + 5760;               // 1,024
    float* sum_bc   = stats;
    float* sumsq_bc = stats + 256;
    float* alpha    = stats + 512;
    float* bbias    = stats + 768;

    k_tr      <<<dim3(NPIX_ / 256), dim3(256), 0, stream>>>(x, xt);
    k_prep    <<<dim3(97),          dim3(256), 0, stream>>>(w_def, w_off, wt_def, wt_off, stats);
    k_conv_off<<<dim3(NPIX_ / 256), dim3(256), 0, stream>>>(xt, wt_off, b_off, offs);
    k_deform  <<<dim3(NPIX_ / 256), dim3(256), 0, stream>>>(xt, offs, wt_def, b_def, yb);
    k_stats   <<<dim3(NPIX_ * 64 / 1024), dim3(256), 0, stream>>>(yb, sum_bc, sumsq_bc);
    k_se      <<<dim3(1),           dim3(256), 0, stream>>>(sum_bc, sumsq_bc, gamma, beta,
                                                            fc1_w, fc1_b, fc2_w, fc2_b, alpha, bbias);
    k_finish  <<<dim3(B_ * COUT_ * 96 * 96 / 512), dim3(256), 0, stream>>>(yb, alpha, bbias, out);
}

// Round 5
// 643.998 us; speedup vs baseline: 1.4415x; 1.4415x over previous
//
#include <hip/hip_runtime.h>
#include <math.h>

#define B_    4
#define CIN_  32
#define COUT_ 64
#define H_    192
#define W_    192
#define HW_   (H_ * W_)        // 36864
#define NPIX_ (B_ * HW_)       // 147456
#define EPS_  1e-5f

// ---------------------------------------------------------------------------
// Kernel 0: fused prep. Blocks [0,576): transpose x (NCHW) -> xt (NHWC).
// Blocks [576,673): weight transposes + stats zeroing.
// ---------------------------------------------------------------------------
__global__ __launch_bounds__(256) void k_pre(
    const float* __restrict__ x, const float* __restrict__ w_def,
    const float* __restrict__ w_off, float* __restrict__ xt,
    float* __restrict__ wt_def, float* __restrict__ wt_off,
    float* __restrict__ stats)
{
    if (blockIdx.x < NPIX_ / 256) {
        const int pid = blockIdx.x * 256 + threadIdx.x;
        const int b   = pid / HW_;
        const int rem = pid - b * HW_;
        const float* xb = x + (size_t)b * CIN_ * HW_ + rem;
        float4 v[8];
#pragma unroll
        for (int j = 0; j < 8; ++j) {
            v[j].x = xb[(j * 4 + 0) * HW_];
            v[j].y = xb[(j * 4 + 1) * HW_];
            v[j].z = xb[(j * 4 + 2) * HW_];
            v[j].w = xb[(j * 4 + 3) * HW_];
        }
        float4* dst = (float4*)(xt + (size_t)pid * 32);
#pragma unroll
        for (int j = 0; j < 8; ++j) dst[j] = v[j];
    } else {
        const int i = (blockIdx.x - NPIX_ / 256) * 256 + threadIdx.x;
        if (i < 18432) {                       // wt_def[kk][c][o64]
            const int o  = i & 63;
            const int c  = (i >> 6) & 31;
            const int kk = i >> 11;
            wt_def[i] = w_def[(o * 32 + c) * 9 + kk];
        } else if (i < 18432 + 5760) {         // wt_off[kk][c][o20]
            const int e  = i - 18432;
            const int o  = e % 20;
            const int t  = e / 20;
            const int c  = t & 31;
            const int kk = t >> 5;
            wt_off[e] = (o < 18) ? w_off[(o * 32 + c) * 9 + kk] : 0.f;
        } else if (i < 18432 + 5760 + 512) {
            stats[i - 18432 - 5760] = 0.f;
        }
    }
}

// ---------------------------------------------------------------------------
// Kernel 1: offsets conv (32 -> 18 ch), NHWC input, kk-level prefetch.
// (R4 form — it did not spill; acc[20]+buffers ~110 VGPRs.)
// ---------------------------------------------------------------------------
__global__ __launch_bounds__(256, 2) void k_conv_off(
    const float* __restrict__ xt, const float* __restrict__ wt,
    const float* __restrict__ b_off, float* __restrict__ offs)
{
    const int pid = blockIdx.x * 256 + threadIdx.x;
    const int b   = pid / HW_;
    const int rem = pid - b * HW_;
    const int h   = rem / W_;
    const int w   = rem - h * W_;
    const float* xb = xt + (size_t)b * HW_ * 32;

    float acc[20];
#pragma unroll
    for (int o = 0; o < 20; ++o) acc[o] = 0.f;

    auto tap = [&](int kk, const float4*& p, float& gate) {
        const int yy = h + kk / 3 - 1;
        const int sx = w + kk % 3 - 1;
        const bool ok = (yy >= 0) & (yy < H_) & (sx >= 0) & (sx < W_);
        const int cy = min(max(yy, 0), H_ - 1);
        const int cx = min(max(sx, 0), W_ - 1);
        p = (const float4*)(xb + (cy * W_ + cx) * 32);
        gate = ok ? 1.f : 0.f;
    };

    const float4* p; float g;
    tap(0, p, g);
    float4 cur[8];
#pragma unroll
    for (int j = 0; j < 8; ++j) cur[j] = p[j];

#pragma unroll 1
    for (int kk = 0; kk < 9; ++kk) {
        float4 nxt[8];
        const float4* np; float ng = 0.f;
        if (kk < 8) {
            tap(kk + 1, np, ng);
#pragma unroll
            for (int j = 0; j < 8; ++j) nxt[j] = np[j];
        }
        const float gg = g;
#pragma unroll
        for (int j = 0; j < 8; ++j) {
            const float4 xv = cur[j];
            const float vs[4] = {xv.x * gg, xv.y * gg, xv.z * gg, xv.w * gg};
#pragma unroll
            for (int e = 0; e < 4; ++e) {
                const int c = j * 4 + e;
                const float4* wr = (const float4*)(wt + (kk * 32 + c) * 20);
                const float a = vs[e];
#pragma unroll
                for (int q = 0; q < 5; ++q) {
                    float4 wv = wr[q];
                    acc[q * 4 + 0] += a * wv.x;
                    acc[q * 4 + 1] += a * wv.y;
                    acc[q * 4 + 2] += a * wv.z;
                    acc[q * 4 + 3] += a * wv.w;
                }
            }
        }
        if (kk < 8) {
            g = ng;
#pragma unroll
            for (int j = 0; j < 8; ++j) cur[j] = nxt[j];
        }
    }

#pragma unroll
    for (int o = 0; o < 18; ++o)
        offs[(b * 18 + o) * HW_ + rem] = acc[o] + b_off[o];
}

// ---------------------------------------------------------------------------
// Kernel 2: deformable conv, COUT split across wave pairs.
// Block = 4 waves: wave (wgrp,half) handles pixels [base+wgrp*64, +64) and
// output channels [half*32, half*32+32). acc[32]; NHWC gathers with A/B
// double-buffered 8-channel chunks; weights via s_load (half is
// readfirstlane-uniform).
// ---------------------------------------------------------------------------
struct Cr { const float4 *q00, *q01, *q10, *q11; float w00, w01, w10, w11; };

__global__ __launch_bounds__(256, 3) void k_deform(
    const float* __restrict__ xt, const float* __restrict__ offs,
    const float* __restrict__ wt, const float* __restrict__ b_def,
    float* __restrict__ y)
{
    const int wid  = __builtin_amdgcn_readfirstlane(threadIdx.x >> 6); // SGPR
    const int half = wid & 1;                                          // uniform
    const int wgrp = wid >> 1;                                         // uniform
    const int lane = threadIdx.x & 63;
    const int pid  = blockIdx.x * 128 + wgrp * 64 + lane;
    const int b    = pid / HW_;
    const int rem  = pid - b * HW_;
    const int h    = rem / W_;
    const int w    = rem - h * W_;
    const float* xb = xt + (size_t)b * HW_ * 32;
    const float* ob = offs + b * 18 * HW_ + rem;
    const float* wh = wt + (half << 5);          // uniform weight base

    float acc[32];
#pragma unroll
    for (int o = 0; o < 32; ++o) acc[o] = 0.f;

    auto mk = [&](int kk) -> Cr {
        const float dy = ob[(2 * kk) * HW_];
        const float dx = ob[(2 * kk + 1) * HW_];
        const float py = (float)(h + kk / 3 - 1) + dy;
        const float px = (float)(w + kk % 3 - 1) + dx;
        const float y0f = floorf(py), x0f = floorf(px);
        const float wy = py - y0f, wx = px - x0f;
        const int iy0 = (int)y0f, ix0 = (int)x0f;
        const int iy1 = iy0 + 1,  ix1 = ix0 + 1;
        const float vy0 = (iy0 >= 0 && iy0 < H_) ? 1.f : 0.f;
        const float vy1 = (iy1 >= 0 && iy1 < H_) ? 1.f : 0.f;
        const float vx0 = (ix0 >= 0 && ix0 < W_) ? 1.f : 0.f;
        const float vx1 = (ix1 >= 0 && ix1 < W_) ? 1.f : 0.f;
        Cr c;
        c.w00 = (1.f - wy) * (1.f - wx) * vy0 * vx0;
        c.w01 = (1.f - wy) * wx * vy0 * vx1;
        c.w10 = wy * (1.f - wx) * vy1 * vx0;
        c.w11 = wy * wx * vy1 * vx1;
        const int cy0 = min(max(iy0, 0), H_ - 1), cy1 = min(max(iy1, 0), H_ - 1);
        const int cx0 = min(max(ix0, 0), W_ - 1), cx1 = min(max(ix1, 0), W_ - 1);
        c.q00 = (const float4*)(xb + (cy0 * W_ + cx0) * 32);
        c.q01 = (const float4*)(xb + (cy0 * W_ + cx1) * 32);
        c.q10 = (const float4*)(xb + (cy1 * W_ + cx0) * 32);
        c.q11 = (const float4*)(xb + (cy1 * W_ + cx1) * 32);
        return c;
    };

    // chunk = 8 channels: 2 float4 from each of the 4 corners
    auto loadc = [&](const Cr& c, int j0, float4* buf) {
#pragma unroll
        for (int j = 0; j < 2; ++j) {
            buf[0 + j] = c.q00[j0 + j];
            buf[2 + j] = c.q01[j0 + j];
            buf[4 + j] = c.q10[j0 + j];
            buf[6 + j] = c.q11[j0 + j];
        }
    };
    auto vburst = [&](const Cr& c, int kk, int c0, const float4* buf) {
        float v[8];
#pragma unroll
        for (int j = 0; j < 2; ++j) {
            const float4 a = buf[0 + j], bq = buf[2 + j];
            const float4 cc = buf[4 + j], d = buf[6 + j];
            v[j * 4 + 0] = c.w00 * a.x + c.w01 * bq.x + c.w10 * cc.x + c.w11 * d.x;
            v[j * 4 + 1] = c.w00 * a.y + c.w01 * bq.y + c.w10 * cc.y + c.w11 * d.y;
            v[j * 4 + 2] = c.w00 * a.z + c.w01 * bq.z + c.w10 * cc.z + c.w11 * d.z;
            v[j * 4 + 3] = c.w00 * a.w + c.w01 * bq.w + c.w10 * cc.w + c.w11 * d.w;
        }
#pragma unroll
        for (int e = 0; e < 8; ++e) {
            const float vc = v[e];
            const float4* wr = (const float4*)(wh + ((kk * 32 + c0 + e) << 6));
#pragma unroll
            for (int q = 0; q < 8; ++q) {       // 32 outputs for this half
                float4 wv = wr[q];
                acc[q * 4 + 0] += vc * wv.x;
                acc[q * 4 + 1] += vc * wv.y;
                acc[q * 4 + 2] += vc * wv.z;
                acc[q * 4 + 3] += vc * wv.w;
            }
        }
    };

    Cr cur = mk(0);
    float4 A[8], Bv[8];
    loadc(cur, 0, A);                       // (kk=0, c0=0)
#pragma unroll 1
    for (int kk = 0; kk < 9; ++kk) {
        loadc(cur, 2, Bv);                  // prefetch c0=8
        vburst(cur, kk, 0, A);
        loadc(cur, 4, A);                   // prefetch c0=16
        vburst(cur, kk, 8, Bv);
        loadc(cur, 6, Bv);                  // prefetch c0=24
        vburst(cur, kk, 16, A);
        Cr nx = (kk < 8) ? mk(kk + 1) : cur;
        if (kk < 8) loadc(nx, 0, A);        // prefetch next kk's c0=0
        vburst(cur, kk, 24, Bv);
        cur = nx;
    }

    float* yp = y + ((size_t)b * COUT_ + half * 32) * HW_ + rem;
#pragma unroll
    for (int q = 0; q < 32; ++q) yp[q * HW_] = acc[q] + b_def[half * 32 + q];
}

// ---------------------------------------------------------------------------
// Kernel 3: per-(b,c) sum / sum-of-squares of y (NCHW planes), float4 loads.
// ---------------------------------------------------------------------------
__global__ __launch_bounds__(256) void k_stats(
    const float* __restrict__ y,
    float* __restrict__ sum_bc, float* __restrict__ sumsq_bc)
{
    const int i = blockIdx.x * 256 + threadIdx.x;
    const float4 v = ((const float4*)y)[i];
    float s = v.x + v.y + v.z + v.w;
    float q = v.x * v.x + v.y * v.y + v.z * v.z + v.w * v.w;
#pragma unroll
    for (int off = 32; off; off >>= 1) {
        s += __shfl_xor(s, off, 64);
        q += __shfl_xor(q, off, 64);
    }
    __shared__ float ls[4], lq[4];
    const int lane = threadIdx.x & 63, wid = threadIdx.x >> 6;
    if (lane == 0) { ls[wid] = s; lq[wid] = q; }
    __syncthreads();
    if (threadIdx.x == 0) {
        const float ts = ls[0] + ls[1] + ls[2] + ls[3];
        const float tq = lq[0] + lq[1] + lq[2] + lq[3];
        const int bc = (i * 4) / HW_;   // uniform within block
        atomicAdd(&sum_bc[bc], ts);
        atomicAdd(&sumsq_bc[bc], tq);
    }
}

// ---------------------------------------------------------------------------
// Kernel 4 (1 block): BN stats + SE MLP -> per-(b,c) affine alpha/bbias.
// ---------------------------------------------------------------------------
__global__ __launch_bounds__(256) void k_se(
    const float* __restrict__ sum_bc, const float* __restrict__ sumsq_bc,
    const float* __restrict__ gamma, const float* __restrict__ beta,
    const float* __restrict__ fc1_w, const float* __restrict__ fc1_b,
    const float* __restrict__ fc2_w, const float* __restrict__ fc2_b,
    float* __restrict__ alpha, float* __restrict__ bbias)
{
    const int tid = threadIdx.x;
    const int b = tid >> 6, c = tid & 63;

    float ch_s = 0.f, ch_q = 0.f;
#pragma unroll
    for (int bb = 0; bb < 4; ++bb) {
        ch_s += sum_bc[bb * 64 + c];
        ch_q += sumsq_bc[bb * 64 + c];
    }
    const float invN = 1.f / (float)(B_ * HW_);
    const float mean = ch_s * invN;
    const float var  = ch_q * invN - mean * mean;
    const float a    = gamma[c] * rsqrtf(var + EPS_);
    const float bi   = beta[c] - mean * a;

    __shared__ float sin_[256];
    sin_[tid] = a * (sum_bc[tid] * (1.f / (float)HW_)) + bi;
    __syncthreads();

    float hv[4];
#pragma unroll
    for (int j = 0; j < 4; ++j) {
        float hs = fc1_b[j];
        for (int cc = 0; cc < 64; ++cc) hs += sin_[b * 64 + cc] * fc1_w[j * 64 + cc];
        hv[j] = fmaxf(hs, 0.f);
    }
    float o = fc2_b[c];
#pragma unroll
    for (int j = 0; j < 4; ++j) o += hv[j] * fc2_w[c * 4 + j];
    const float s = 1.f / (1.f + expf(-o));

    alpha[tid] = a * s;
    bbias[tid] = bi * s;
}

// ---------------------------------------------------------------------------
// Kernel 5: fused affine(BN*SE) + ReLU + 2x2 maxpool -> out (4,64,96,96).
// ---------------------------------------------------------------------------
__global__ __launch_bounds__(256) void k_finish(
    const float* __restrict__ y,
    const float* __restrict__ alpha, const float* __restrict__ bbias,
    float* __restrict__ out)
{
    const int t    = blockIdx.x * 256 + threadIdx.x;
    const int opix = t * 2;
    const int bc   = opix / (96 * 96);
    const int rem  = opix - bc * (96 * 96);
    const int oh   = rem / 96, ow = rem - oh * 96;
    const float al = alpha[bc], bb = bbias[bc];
    const float* yp = y + (size_t)bc * HW_ + (2 * oh) * W_ + 2 * ow;
    const float4 r0 = *(const float4*)yp;
    const float4 r1 = *(const float4*)(yp + W_);
    float2 st;
    st.x = fmaxf(fmaxf(fmaxf(fmaf(r0.x, al, bb), fmaf(r0.y, al, bb)),
                       fmaxf(fmaf(r1.x, al, bb), fmaf(r1.y, al, bb))), 0.f);
    st.y = fmaxf(fmaxf(fmaxf(fmaf(r0.z, al, bb), fmaf(r0.w, al, bb)),
                       fmaxf(fmaf(r1.z, al, bb), fmaf(r1.w, al, bb))), 0.f);
    *(float2*)(out + opix) = st;
}

// ---------------------------------------------------------------------------
extern "C" void kernel_launch(void* const* d_in, const int* in_sizes, int n_in,
                              void* d_out, int out_size, void* d_ws, size_t ws_size,
                              hipStream_t stream)
{
    const float* x     = (const float*)d_in[0];
    const float* w_off = (const float*)d_in[1];
    const float* b_off = (const float*)d_in[2];
    const float* w_def = (const float*)d_in[3];
    const float* b_def = (const float*)d_in[4];
    const float* gamma = (const float*)d_in[5];
    const float* beta  = (const float*)d_in[6];
    const float* fc1_w = (const float*)d_in[7];
    const float* fc1_b = (const float*)d_in[8];
    const float* fc2_w = (const float*)d_in[9];
    const float* fc2_b = (const float*)d_in[10];
    float* out = (float*)d_out;

    float* ws   = (float*)d_ws;
    float* offs   = ws;                          // 2,654,208 floats
    float* yb     = offs + 2654208;              // 9,437,184 floats
    float* xt     = yb + 9437184;                // 4,718,592 floats (NHWC x)
    float* wt_def = xt + 4718592;                // 18,432
    float* wt_off = wt_def + 18432;              // 5,760
    float* stats  = wt_off + 5760;               // 1,024
    float* sum_bc   = stats;
    float* sumsq_bc = stats + 256;
    float* alpha    = stats + 512;
    float* bbias    = stats + 768;

    k_pre     <<<dim3(NPIX_ / 256 + 97), dim3(256), 0, stream>>>(
                  x, w_def, w_off, xt, wt_def, wt_off, stats);
    k_conv_off<<<dim3(NPIX_ / 256), dim3(256), 0, stream>>>(xt, wt_off, b_off, offs);
    k_deform  <<<dim3(NPIX_ / 128), dim3(256), 0, stream>>>(xt, offs, wt_def, b_def, yb);
    k_stats   <<<dim3(NPIX_ * 64 / 1024), dim3(256), 0, stream>>>(yb, sum_bc, sumsq_bc);
    k_se      <<<dim3(1), dim3(256), 0, stream>>>(sum_bc, sumsq_bc, gamma, beta,
                                                  fc1_w, fc1_b, fc2_w, fc2_b, alpha, bbias);
    k_finish  <<<dim3(B_ * COUT_ * 96 * 96 / 512), dim3(256), 0, stream>>>(yb, alpha, bbias, out);
}

// Round 6
// 394.554 us; speedup vs baseline: 2.3528x; 1.6322x over previous
//
#include <hip/hip_runtime.h>
#include <math.h>

#define B_    4
#define CIN_  32
#define COUT_ 64
#define H_    192
#define W_    192
#define HW_   (H_ * W_)        // 36864
#define NPIX_ (B_ * HW_)       // 147456
#define EPS_  1e-5f

// ---------------------------------------------------------------------------
// Kernel 0: fused prep. Blocks [0,576): transpose x (NCHW) -> xt (NHWC).
// Blocks [576,673): weight transposes + stats zeroing.
// ---------------------------------------------------------------------------
__global__ __launch_bounds__(256) void k_pre(
    const float* __restrict__ x, const float* __restrict__ w_def,
    const float* __restrict__ w_off, float* __restrict__ xt,
    float* __restrict__ wt_def, float* __restrict__ wt_off,
    float* __restrict__ stats)
{
    if (blockIdx.x < NPIX_ / 256) {
        const int pid = blockIdx.x * 256 + threadIdx.x;
        const int b   = pid / HW_;
        const int rem = pid - b * HW_;
        const float* xb = x + (size_t)b * CIN_ * HW_ + rem;
        float4 v[8];
#pragma unroll
        for (int j = 0; j < 8; ++j) {
            v[j].x = xb[(j * 4 + 0) * HW_];
            v[j].y = xb[(j * 4 + 1) * HW_];
            v[j].z = xb[(j * 4 + 2) * HW_];
            v[j].w = xb[(j * 4 + 3) * HW_];
        }
        float4* dst = (float4*)(xt + (size_t)pid * 32);
#pragma unroll
        for (int j = 0; j < 8; ++j) dst[j] = v[j];
    } else {
        const int i = (blockIdx.x - NPIX_ / 256) * 256 + threadIdx.x;
        if (i < 18432) {                       // wt_def[kk][c][o64]
            const int o  = i & 63;
            const int c  = (i >> 6) & 31;
            const int kk = i >> 11;
            wt_def[i] = w_def[(o * 32 + c) * 9 + kk];
        } else if (i < 18432 + 5760) {         // wt_off[kk][c][o20]
            const int e  = i - 18432;
            const int o  = e % 20;
            const int t  = e / 20;
            const int c  = t & 31;
            const int kk = t >> 5;
            wt_off[e] = (o < 18) ? w_off[(o * 32 + c) * 9 + kk] : 0.f;
        } else if (i < 18432 + 5760 + 512) {
            stats[i - 18432 - 5760] = 0.f;
        }
    }
}

// ---------------------------------------------------------------------------
// Kernel 1: offsets conv (32 -> 18 ch), NHWC input. Serial 8-channel chunks,
// low register pressure (acc[20] + 8-wide buffer). Block = 128 threads for
// finer CU balance (grid 1152).
// ---------------------------------------------------------------------------
__global__ __launch_bounds__(128, 4) void k_conv_off(
    const float* __restrict__ xt, const float* __restrict__ wt,
    const float* __restrict__ b_off, float* __restrict__ offs)
{
    const int pid = blockIdx.x * 128 + threadIdx.x;
    const int b   = pid / HW_;
    const int rem = pid - b * HW_;
    const int h   = rem / W_;
    const int w   = rem - h * W_;
    const float* xb = xt + (size_t)b * HW_ * 32;

    float acc[20];
#pragma unroll
    for (int o = 0; o < 20; ++o) acc[o] = 0.f;

#pragma unroll 1
    for (int kk = 0; kk < 9; ++kk) {
        const int yy = h + kk / 3 - 1;
        const int sx = w + kk % 3 - 1;
        const bool ok = (yy >= 0) & (yy < H_) & (sx >= 0) & (sx < W_);
        const int cy = min(max(yy, 0), H_ - 1);
        const int cx = min(max(sx, 0), W_ - 1);
        const float g = ok ? 1.f : 0.f;
        const float* cp = xb + (cy * W_ + cx) * 32;

#pragma unroll 1
        for (int c8 = 0; c8 < 4; ++c8) {
            const float4 x0 = *(const float4*)(cp + c8 * 8);
            const float4 x1 = *(const float4*)(cp + c8 * 8 + 4);
            float vs[8] = {x0.x * g, x0.y * g, x0.z * g, x0.w * g,
                           x1.x * g, x1.y * g, x1.z * g, x1.w * g};
#pragma unroll
            for (int e = 0; e < 8; ++e) {
                const float4* wr = (const float4*)(wt + (kk * 32 + c8 * 8 + e) * 20);
                const float a = vs[e];
#pragma unroll
                for (int q = 0; q < 5; ++q) {
                    float4 wv = wr[q];
                    acc[q * 4 + 0] += a * wv.x;
                    acc[q * 4 + 1] += a * wv.y;
                    acc[q * 4 + 2] += a * wv.z;
                    acc[q * 4 + 3] += a * wv.w;
                }
            }
        }
    }

#pragma unroll
    for (int o = 0; o < 18; ++o)
        offs[(b * 18 + o) * HW_ + rem] = acc[o] + b_off[o];
}

// ---------------------------------------------------------------------------
// Kernel 2: deformable conv. Block = 4 waves: wave (wgrp,half) handles
// pixels [blk*128 + wgrp*64, +64) and output channels [half*32, +32).
// acc[32]; NHWC gathers in serial 8-channel chunks (8 float4 loads ->
// bilinear v[8] -> 256-FMA burst). Weights via uniform s_load. NO explicit
// double-buffer: latency hidden by 4 waves/SIMD (launch_bounds(256,4),
// 128-VGPR cap, est. need ~100 -> no spill).
// ---------------------------------------------------------------------------
__global__ __launch_bounds__(256, 4) void k_deform(
    const float* __restrict__ xt, const float* __restrict__ offs,
    const float* __restrict__ wt, const float* __restrict__ b_def,
    float* __restrict__ y)
{
    const int tid  = threadIdx.x;
    const int half = __builtin_amdgcn_readfirstlane((tid >> 6) & 1);  // uniform
    const int wgrp = tid >> 7;                                        // 0..1
    const int lane = tid & 63;
    const int pid  = blockIdx.x * 128 + wgrp * 64 + lane;
    const int b    = pid / HW_;
    const int rem  = pid - b * HW_;
    const int h    = rem / W_;
    const int w    = rem - h * W_;
    const float* xb = xt + (size_t)b * HW_ * 32;
    const float* ob = offs + b * 18 * HW_ + rem;

    float acc[32];
#pragma unroll
    for (int o = 0; o < 32; ++o) acc[o] = 0.f;

#pragma unroll 1
    for (int kk = 0; kk < 9; ++kk) {
        const float dy = ob[(2 * kk) * HW_];
        const float dx = ob[(2 * kk + 1) * HW_];
        const float py = (float)(h + kk / 3 - 1) + dy;
        const float px = (float)(w + kk % 3 - 1) + dx;
        const float y0f = floorf(py), x0f = floorf(px);
        const float wy = py - y0f, wx = px - x0f;
        const int iy0 = (int)y0f, ix0 = (int)x0f;
        const int iy1 = iy0 + 1,  ix1 = ix0 + 1;
        const float vy0 = (iy0 >= 0 && iy0 < H_) ? 1.f : 0.f;
        const float vy1 = (iy1 >= 0 && iy1 < H_) ? 1.f : 0.f;
        const float vx0 = (ix0 >= 0 && ix0 < W_) ? 1.f : 0.f;
        const float vx1 = (ix1 >= 0 && ix1 < W_) ? 1.f : 0.f;
        const float w00 = (1.f - wy) * (1.f - wx) * vy0 * vx0;
        const float w01 = (1.f - wy) * wx * vy0 * vx1;
        const float w10 = wy * (1.f - wx) * vy1 * vx0;
        const float w11 = wy * wx * vy1 * vx1;
        const int cy0 = min(max(iy0, 0), H_ - 1), cy1 = min(max(iy1, 0), H_ - 1);
        const int cx0 = min(max(ix0, 0), W_ - 1), cx1 = min(max(ix1, 0), W_ - 1);
        const int o00 = (cy0 * W_ + cx0) * 32, o01 = (cy0 * W_ + cx1) * 32;
        const int o10 = (cy1 * W_ + cx0) * 32, o11 = (cy1 * W_ + cx1) * 32;

#pragma unroll 1
        for (int c8 = 0; c8 < 4; ++c8) {
            const int co = c8 * 8;
            const float4 a0 = *(const float4*)(xb + o00 + co);
            const float4 b0 = *(const float4*)(xb + o01 + co);
            const float4 c0 = *(const float4*)(xb + o10 + co);
            const float4 d0 = *(const float4*)(xb + o11 + co);
            const float4 a1 = *(const float4*)(xb + o00 + co + 4);
            const float4 b1 = *(const float4*)(xb + o01 + co + 4);
            const float4 c1 = *(const float4*)(xb + o10 + co + 4);
            const float4 d1 = *(const float4*)(xb + o11 + co + 4);
            float v[8];
            v[0] = w00 * a0.x + w01 * b0.x + w10 * c0.x + w11 * d0.x;
            v[1] = w00 * a0.y + w01 * b0.y + w10 * c0.y + w11 * d0.y;
            v[2] = w00 * a0.z + w01 * b0.z + w10 * c0.z + w11 * d0.z;
            v[3] = w00 * a0.w + w01 * b0.w + w10 * c0.w + w11 * d0.w;
            v[4] = w00 * a1.x + w01 * b1.x + w10 * c1.x + w11 * d1.x;
            v[5] = w00 * a1.y + w01 * b1.y + w10 * c1.y + w11 * d1.y;
            v[6] = w00 * a1.z + w01 * b1.z + w10 * c1.z + w11 * d1.z;
            v[7] = w00 * a1.w + w01 * b1.w + w10 * c1.w + w11 * d1.w;
#pragma unroll
            for (int e = 0; e < 8; ++e) {
                const float vc = v[e];
                const float4* wr =
                    (const float4*)(wt + ((kk * 32 + co + e) << 6) + (half << 5));
#pragma unroll
                for (int q = 0; q < 8; ++q) {       // 32 outputs for this half
                    float4 wv = wr[q];
                    acc[q * 4 + 0] += vc * wv.x;
                    acc[q * 4 + 1] += vc * wv.y;
                    acc[q * 4 + 2] += vc * wv.z;
                    acc[q * 4 + 3] += vc * wv.w;
                }
            }
        }
    }

    float* yp = y + ((size_t)b * COUT_ + half * 32) * HW_ + rem;
#pragma unroll
    for (int q = 0; q < 32; ++q) yp[q * HW_] = acc[q] + b_def[half * 32 + q];
}

// ---------------------------------------------------------------------------
// Kernel 3: per-(b,c) sum / sum-of-squares of y (NCHW planes), float4 loads.
// ---------------------------------------------------------------------------
__global__ __launch_bounds__(256) void k_stats(
    const float* __restrict__ y,
    float* __restrict__ sum_bc, float* __restrict__ sumsq_bc)
{
    const int i = blockIdx.x * 256 + threadIdx.x;
    const float4 v = ((const float4*)y)[i];
    float s = v.x + v.y + v.z + v.w;
    float q = v.x * v.x + v.y * v.y + v.z * v.z + v.w * v.w;
#pragma unroll
    for (int off = 32; off; off >>= 1) {
        s += __shfl_xor(s, off, 64);
        q += __shfl_xor(q, off, 64);
    }
    __shared__ float ls[4], lq[4];
    const int lane = threadIdx.x & 63, wid = threadIdx.x >> 6;
    if (lane == 0) { ls[wid] = s; lq[wid] = q; }
    __syncthreads();
    if (threadIdx.x == 0) {
        const float ts = ls[0] + ls[1] + ls[2] + ls[3];
        const float tq = lq[0] + lq[1] + lq[2] + lq[3];
        const int bc = (i * 4) / HW_;   // uniform within block
        atomicAdd(&sum_bc[bc], ts);
        atomicAdd(&sumsq_bc[bc], tq);
    }
}

// ---------------------------------------------------------------------------
// Kernel 4 (1 block): BN stats + SE MLP -> per-(b,c) affine alpha/bbias.
// ---------------------------------------------------------------------------
__global__ __launch_bounds__(256) void k_se(
    const float* __restrict__ sum_bc, const float* __restrict__ sumsq_bc,
    const float* __restrict__ gamma, const float* __restrict__ beta,
    const float* __restrict__ fc1_w, const float* __restrict__ fc1_b,
    const float* __restrict__ fc2_w, const float* __restrict__ fc2_b,
    float* __restrict__ alpha, float* __restrict__ bbias)
{
    const int tid = threadIdx.x;
    const int b = tid >> 6, c = tid & 63;

    float ch_s = 0.f, ch_q = 0.f;
#pragma unroll
    for (int bb = 0; bb < 4; ++bb) {
        ch_s += sum_bc[bb * 64 + c];
        ch_q += sumsq_bc[bb * 64 + c];
    }
    const float invN = 1.f / (float)(B_ * HW_);
    const float mean = ch_s * invN;
    const float var  = ch_q * invN - mean * mean;
    const float a    = gamma[c] * rsqrtf(var + EPS_);
    const float bi   = beta[c] - mean * a;

    __shared__ float sin_[256];
    sin_[tid] = a * (sum_bc[tid] * (1.f / (float)HW_)) + bi;
    __syncthreads();

    float hv[4];
#pragma unroll
    for (int j = 0; j < 4; ++j) {
        float hs = fc1_b[j];
        for (int cc = 0; cc < 64; ++cc) hs += sin_[b * 64 + cc] * fc1_w[j * 64 + cc];
        hv[j] = fmaxf(hs, 0.f);
    }
    float o = fc2_b[c];
#pragma unroll
    for (int j = 0; j < 4; ++j) o += hv[j] * fc2_w[c * 4 + j];
    const float s = 1.f / (1.f + expf(-o));

    alpha[tid] = a * s;
    bbias[tid] = bi * s;
}

// ---------------------------------------------------------------------------
// Kernel 5: fused affine(BN*SE) + ReLU + 2x2 maxpool -> out (4,64,96,96).
// ---------------------------------------------------------------------------
__global__ __launch_bounds__(256) void k_finish(
    const float* __restrict__ y,
    const float* __restrict__ alpha, const float* __restrict__ bbias,
    float* __restrict__ out)
{
    const int t    = blockIdx.x * 256 + threadIdx.x;
    const int opix = t * 2;
    const int bc   = opix / (96 * 96);
    const int rem  = opix - bc * (96 * 96);
    const int oh   = rem / 96, ow = rem - oh * 96;
    const float al = alpha[bc], bb = bbias[bc];
    const float* yp = y + (size_t)bc * HW_ + (2 * oh) * W_ + 2 * ow;
    const float4 r0 = *(const float4*)yp;
    const float4 r1 = *(const float4*)(yp + W_);
    float2 st;
    st.x = fmaxf(fmaxf(fmaxf(fmaf(r0.x, al, bb), fmaf(r0.y, al, bb)),
                       fmaxf(fmaf(r1.x, al, bb), fmaf(r1.y, al, bb))), 0.f);
    st.y = fmaxf(fmaxf(fmaxf(fmaf(r0.z, al, bb), fmaf(r0.w, al, bb)),
                       fmaxf(fmaf(r1.z, al, bb), fmaf(r1.w, al, bb))), 0.f);
    *(float2*)(out + opix) = st;
}

// ---------------------------------------------------------------------------
extern "C" void kernel_launch(void* const* d_in, const int* in_sizes, int n_in,
                              void* d_out, int out_size, void* d_ws, size_t ws_size,
                              hipStream_t stream)
{
    const float* x     = (const float*)d_in[0];
    const float* w_off = (const float*)d_in[1];
    const float* b_off = (const float*)d_in[2];
    const float* w_def = (const float*)d_in[3];
    const float* b_def = (const float*)d_in[4];
    const float* gamma = (const float*)d_in[5];
    const float* beta  = (const float*)d_in[6];
    const float* fc1_w = (const float*)d_in[7];
    const float* fc1_b = (const float*)d_in[8];
    const float* fc2_w = (const float*)d_in[9];
    const float* fc2_b = (const float*)d_in[10];
    float* out = (float*)d_out;

    float* ws   = (float*)d_ws;
    float* offs   = ws;                          // 2,654,208 floats
    float* yb     = offs + 2654208;              // 9,437,184 floats
    float* xt     = yb + 9437184;                // 4,718,592 floats (NHWC x)
    float* wt_def = xt + 4718592;                // 18,432
    float* wt_off = wt_def + 18432;              // 5,760
    float* stats  = wt_off + 5760;               // 1,024
    float* sum_bc   = stats;
    float* sumsq_bc = stats + 256;
    float* alpha    = stats + 512;
    float* bbias    = stats + 768;

    k_pre     <<<dim3(NPIX_ / 256 + 97), dim3(256), 0, stream>>>(
                  x, w_def, w_off, xt, wt_def, wt_off, stats);
    k_conv_off<<<dim3(NPIX_ / 128), dim3(128), 0, stream>>>(xt, wt_off, b_off, offs);
    k_deform  <<<dim3(NPIX_ / 128), dim3(256), 0, stream>>>(xt, offs, wt_def, b_def, yb);
    k_stats   <<<dim3(NPIX_ * 64 / 1024), dim3(256), 0, stream>>>(yb, sum_bc, sumsq_bc);
    k_se      <<<dim3(1), dim3(256), 0, stream>>>(sum_bc, sumsq_bc, gamma, beta,
                                                  fc1_w, fc1_b, fc2_w, fc2_b, alpha, bbias);
    k_finish  <<<dim3(B_ * COUT_ * 96 * 96 / 512), dim3(256), 0, stream>>>(yb, alpha, bbias, out);
}

// Round 7
// 328.294 us; speedup vs baseline: 2.8277x; 1.2018x over previous
//
#include <hip/hip_runtime.h>
#include <math.h>

#define B_    4
#define CIN_  32
#define COUT_ 64
#define H_    192
#define W_    192
#define HW_   (H_ * W_)        // 36864
#define NPIX_ (B_ * HW_)       // 147456
#define EPS_  1e-5f

// XCD-aware swizzle: grid 1152 = 8 XCDs * 144. Assuming round-robin
// blockIdx->XCD dispatch, this gives XCD k a contiguous half-image-plane
// (2.36 MB of xt + 1.33 MB of offs < 4 MB per-XCD L2). Perf-only heuristic.
static __device__ __forceinline__ int swz1152(int blk) {
    return ((blk & 7) * 144) + (blk >> 3);
}

// ---------------------------------------------------------------------------
// Kernel 0: fused prep. Blocks [0,576): transpose x (NCHW) -> xt (NHWC).
// Blocks [576,673): weight transposes + stats zeroing.
// ---------------------------------------------------------------------------
__global__ __launch_bounds__(256) void k_pre(
    const float* __restrict__ x, const float* __restrict__ w_def,
    const float* __restrict__ w_off, float* __restrict__ xt,
    float* __restrict__ wt_def, float* __restrict__ wt_off,
    float* __restrict__ stats)
{
    if (blockIdx.x < NPIX_ / 256) {
        const int pid = blockIdx.x * 256 + threadIdx.x;
        const int b   = pid / HW_;
        const int rem = pid - b * HW_;
        const float* xb = x + (size_t)b * CIN_ * HW_ + rem;
        float4 v[8];
#pragma unroll
        for (int j = 0; j < 8; ++j) {
            v[j].x = xb[(j * 4 + 0) * HW_];
            v[j].y = xb[(j * 4 + 1) * HW_];
            v[j].z = xb[(j * 4 + 2) * HW_];
            v[j].w = xb[(j * 4 + 3) * HW_];
        }
        float4* dst = (float4*)(xt + (size_t)pid * 32);
#pragma unroll
        for (int j = 0; j < 8; ++j) dst[j] = v[j];
    } else {
        const int i = (blockIdx.x - NPIX_ / 256) * 256 + threadIdx.x;
        if (i < 18432) {                       // wt_def[kk][c][o64]
            const int o  = i & 63;
            const int c  = (i >> 6) & 31;
            const int kk = i >> 11;
            wt_def[i] = w_def[(o * 32 + c) * 9 + kk];
        } else if (i < 18432 + 5760) {         // wt_off[kk][c][o20]
            const int e  = i - 18432;
            const int o  = e % 20;
            const int t  = e / 20;
            const int c  = t & 31;
            const int kk = t >> 5;
            wt_off[e] = (o < 18) ? w_off[(o * 32 + c) * 9 + kk] : 0.f;
        } else if (i < 18432 + 5760 + 512) {
            stats[i - 18432 - 5760] = 0.f;
        }
    }
}

// ---------------------------------------------------------------------------
// Kernel 1: offsets conv (32 -> 18 ch), NHWC input. Serial 8-channel chunks,
// XCD-swizzled blocks.
// ---------------------------------------------------------------------------
__global__ __launch_bounds__(128, 4) void k_conv_off(
    const float* __restrict__ xt, const float* __restrict__ wt,
    const float* __restrict__ b_off, float* __restrict__ offs)
{
    const int pid = swz1152(blockIdx.x) * 128 + threadIdx.x;
    const int b   = pid / HW_;
    const int rem = pid - b * HW_;
    const int h   = rem / W_;
    const int w   = rem - h * W_;
    const float* xb = xt + (size_t)b * HW_ * 32;

    float acc[20];
#pragma unroll
    for (int o = 0; o < 20; ++o) acc[o] = 0.f;

#pragma unroll 1
    for (int kk = 0; kk < 9; ++kk) {
        const int yy = h + kk / 3 - 1;
        const int sx = w + kk % 3 - 1;
        const bool ok = (yy >= 0) & (yy < H_) & (sx >= 0) & (sx < W_);
        const int cy = min(max(yy, 0), H_ - 1);
        const int cx = min(max(sx, 0), W_ - 1);
        const float g = ok ? 1.f : 0.f;
        const float* cp = xb + (cy * W_ + cx) * 32;

#pragma unroll 1
        for (int c8 = 0; c8 < 4; ++c8) {
            const float4 x0 = *(const float4*)(cp + c8 * 8);
            const float4 x1 = *(const float4*)(cp + c8 * 8 + 4);
            float vs[8] = {x0.x * g, x0.y * g, x0.z * g, x0.w * g,
                           x1.x * g, x1.y * g, x1.z * g, x1.w * g};
#pragma unroll
            for (int e = 0; e < 8; ++e) {
                const float4* wr = (const float4*)(wt + (kk * 32 + c8 * 8 + e) * 20);
                const float a = vs[e];
#pragma unroll
                for (int q = 0; q < 5; ++q) {
                    float4 wv = wr[q];
                    acc[q * 4 + 0] += a * wv.x;
                    acc[q * 4 + 1] += a * wv.y;
                    acc[q * 4 + 2] += a * wv.z;
                    acc[q * 4 + 3] += a * wv.w;
                }
            }
        }
    }

#pragma unroll
    for (int o = 0; o < 18; ++o)
        offs[(b * 18 + o) * HW_ + rem] = acc[o] + b_off[o];
}

// ---------------------------------------------------------------------------
// Kernel 2: deformable conv. Block = 4 waves: wave (wgrp,half) handles
// pixels [blkpix + wgrp*64, +64) and output channels [half*32, +32).
// acc[32]; NHWC gathers in serial 8-channel chunks; weights via uniform
// s_load; XCD-swizzled blocks; next-kk offsets preloaded.
// ---------------------------------------------------------------------------
__global__ __launch_bounds__(256, 4) void k_deform(
    const float* __restrict__ xt, const float* __restrict__ offs,
    const float* __restrict__ wt, const float* __restrict__ b_def,
    float* __restrict__ y)
{
    const int tid  = threadIdx.x;
    const int half = __builtin_amdgcn_readfirstlane((tid >> 6) & 1);  // uniform
    const int wgrp = tid >> 7;                                        // 0..1
    const int lane = tid & 63;
    const int pid  = swz1152(blockIdx.x) * 128 + wgrp * 64 + lane;
    const int b    = pid / HW_;
    const int rem  = pid - b * HW_;
    const int h    = rem / W_;
    const int w    = rem - h * W_;
    const float* xb = xt + (size_t)b * HW_ * 32;
    const float* ob = offs + b * 18 * HW_ + rem;

    float acc[32];
#pragma unroll
    for (int o = 0; o < 32; ++o) acc[o] = 0.f;

    float dy = ob[0];
    float dx = ob[HW_];

#pragma unroll 1
    for (int kk = 0; kk < 9; ++kk) {
        float ndy = 0.f, ndx = 0.f;
        if (kk < 8) {                       // preload next kk's offsets early
            ndy = ob[(2 * kk + 2) * HW_];
            ndx = ob[(2 * kk + 3) * HW_];
        }
        const float py = (float)(h + kk / 3 - 1) + dy;
        const float px = (float)(w + kk % 3 - 1) + dx;
        const float y0f = floorf(py), x0f = floorf(px);
        const float wy = py - y0f, wx = px - x0f;
        const int iy0 = (int)y0f, ix0 = (int)x0f;
        const int iy1 = iy0 + 1,  ix1 = ix0 + 1;
        const float vy0 = (iy0 >= 0 && iy0 < H_) ? 1.f : 0.f;
        const float vy1 = (iy1 >= 0 && iy1 < H_) ? 1.f : 0.f;
        const float vx0 = (ix0 >= 0 && ix0 < W_) ? 1.f : 0.f;
        const float vx1 = (ix1 >= 0 && ix1 < W_) ? 1.f : 0.f;
        const float w00 = (1.f - wy) * (1.f - wx) * vy0 * vx0;
        const float w01 = (1.f - wy) * wx * vy0 * vx1;
        const float w10 = wy * (1.f - wx) * vy1 * vx0;
        const float w11 = wy * wx * vy1 * vx1;
        const int cy0 = min(max(iy0, 0), H_ - 1), cy1 = min(max(iy1, 0), H_ - 1);
        const int cx0 = min(max(ix0, 0), W_ - 1), cx1 = min(max(ix1, 0), W_ - 1);
        const int o00 = (cy0 * W_ + cx0) * 32, o01 = (cy0 * W_ + cx1) * 32;
        const int o10 = (cy1 * W_ + cx0) * 32, o11 = (cy1 * W_ + cx1) * 32;

#pragma unroll 1
        for (int c8 = 0; c8 < 4; ++c8) {
            const int co = c8 * 8;
            const float4 a0 = *(const float4*)(xb + o00 + co);
            const float4 b0 = *(const float4*)(xb + o01 + co);
            const float4 c0 = *(const float4*)(xb + o10 + co);
            const float4 d0 = *(const float4*)(xb + o11 + co);
            const float4 a1 = *(const float4*)(xb + o00 + co + 4);
            const float4 b1 = *(const float4*)(xb + o01 + co + 4);
            const float4 c1 = *(const float4*)(xb + o10 + co + 4);
            const float4 d1 = *(const float4*)(xb + o11 + co + 4);
            float v[8];
            v[0] = w00 * a0.x + w01 * b0.x + w10 * c0.x + w11 * d0.x;
            v[1] = w00 * a0.y + w01 * b0.y + w10 * c0.y + w11 * d0.y;
            v[2] = w00 * a0.z + w01 * b0.z + w10 * c0.z + w11 * d0.z;
            v[3] = w00 * a0.w + w01 * b0.w + w10 * c0.w + w11 * d0.w;
            v[4] = w00 * a1.x + w01 * b1.x + w10 * c1.x + w11 * d1.x;
            v[5] = w00 * a1.y + w01 * b1.y + w10 * c1.y + w11 * d1.y;
            v[6] = w00 * a1.z + w01 * b1.z + w10 * c1.z + w11 * d1.z;
            v[7] = w00 * a1.w + w01 * b1.w + w10 * c1.w + w11 * d1.w;
#pragma unroll
            for (int e = 0; e < 8; ++e) {
                const float vc = v[e];
                const float4* wr =
                    (const float4*)(wt + ((kk * 32 + co + e) << 6) + (half << 5));
#pragma unroll
                for (int q = 0; q < 8; ++q) {       // 32 outputs for this half
                    float4 wv = wr[q];
                    acc[q * 4 + 0] += vc * wv.x;
                    acc[q * 4 + 1] += vc * wv.y;
                    acc[q * 4 + 2] += vc * wv.z;
                    acc[q * 4 + 3] += vc * wv.w;
                }
            }
        }
        dy = ndy; dx = ndx;
    }

    float* yp = y + ((size_t)b * COUT_ + half * 32) * HW_ + rem;
#pragma unroll
    for (int q = 0; q < 32; ++q) yp[q * HW_] = acc[q] + b_def[half * 32 + q];
}

// ---------------------------------------------------------------------------
// Kernel 3: per-(b,c) sum / sum-of-squares of y (NCHW planes), float4 loads.
// ---------------------------------------------------------------------------
__global__ __launch_bounds__(256) void k_stats(
    const float* __restrict__ y,
    float* __restrict__ sum_bc, float* __restrict__ sumsq_bc)
{
    const int i = blockIdx.x * 256 + threadIdx.x;
    const float4 v = ((const float4*)y)[i];
    float s = v.x + v.y + v.z + v.w;
    float q = v.x * v.x + v.y * v.y + v.z * v.z + v.w * v.w;
#pragma unroll
    for (int off = 32; off; off >>= 1) {
        s += __shfl_xor(s, off, 64);
        q += __shfl_xor(q, off, 64);
    }
    __shared__ float ls[4], lq[4];
    const int lane = threadIdx.x & 63, wid = threadIdx.x >> 6;
    if (lane == 0) { ls[wid] = s; lq[wid] = q; }
    __syncthreads();
    if (threadIdx.x == 0) {
        const float ts = ls[0] + ls[1] + ls[2] + ls[3];
        const float tq = lq[0] + lq[1] + lq[2] + lq[3];
        const int bc = (i * 4) / HW_;   // uniform within block
        atomicAdd(&sum_bc[bc], ts);
        atomicAdd(&sumsq_bc[bc], tq);
    }
}

// ---------------------------------------------------------------------------
// Kernel 4 (1 block): BN stats + SE MLP -> per-(b,c) affine alpha/bbias.
// ---------------------------------------------------------------------------
__global__ __launch_bounds__(256) void k_se(
    const float* __restrict__ sum_bc, const float* __restrict__ sumsq_bc,
    const float* __restrict__ gamma, const float* __restrict__ beta,
    const float* __restrict__ fc1_w, const float* __restrict__ fc1_b,
    const float* __restrict__ fc2_w, const float* __restrict__ fc2_b,
    float* __restrict__ alpha, float* __restrict__ bbias)
{
    const int tid = threadIdx.x;
    const int b = tid >> 6, c = tid & 63;

    float ch_s = 0.f, ch_q = 0.f;
#pragma unroll
    for (int bb = 0; bb < 4; ++bb) {
        ch_s += sum_bc[bb * 64 + c];
        ch_q += sumsq_bc[bb * 64 + c];
    }
    const float invN = 1.f / (float)(B_ * HW_);
    const float mean = ch_s * invN;
    const float var  = ch_q * invN - mean * mean;
    const float a    = gamma[c] * rsqrtf(var + EPS_);
    const float bi   = beta[c] - mean * a;

    __shared__ float sin_[256];
    sin_[tid] = a * (sum_bc[tid] * (1.f / (float)HW_)) + bi;
    __syncthreads();

    float hv[4];
#pragma unroll
    for (int j = 0; j < 4; ++j) {
        float hs = fc1_b[j];
        for (int cc = 0; cc < 64; ++cc) hs += sin_[b * 64 + cc] * fc1_w[j * 64 + cc];
        hv[j] = fmaxf(hs, 0.f);
    }
    float o = fc2_b[c];
#pragma unroll
    for (int j = 0; j < 4; ++j) o += hv[j] * fc2_w[c * 4 + j];
    const float s = 1.f / (1.f + expf(-o));

    alpha[tid] = a * s;
    bbias[tid] = bi * s;
}

// ---------------------------------------------------------------------------
// Kernel 5: fused affine(BN*SE) + ReLU + 2x2 maxpool -> out (4,64,96,96).
// ---------------------------------------------------------------------------
__global__ __launch_bounds__(256) void k_finish(
    const float* __restrict__ y,
    const float* __restrict__ alpha, const float* __restrict__ bbias,
    float* __restrict__ out)
{
    const int t    = blockIdx.x * 256 + threadIdx.x;
    const int opix = t * 2;
    const int bc   = opix / (96 * 96);
    const int rem  = opix - bc * (96 * 96);
    const int oh   = rem / 96, ow = rem - oh * 96;
    const float al = alpha[bc], bb = bbias[bc];
    const float* yp = y + (size_t)bc * HW_ + (2 * oh) * W_ + 2 * ow;
    const float4 r0 = *(const float4*)yp;
    const float4 r1 = *(const float4*)(yp + W_);
    float2 st;
    st.x = fmaxf(fmaxf(fmaxf(fmaf(r0.x, al, bb), fmaf(r0.y, al, bb)),
                       fmaxf(fmaf(r1.x, al, bb), fmaf(r1.y, al, bb))), 0.f);
    st.y = fmaxf(fmaxf(fmaxf(fmaf(r0.z, al, bb), fmaf(r0.w, al, bb)),
                       fmaxf(fmaf(r1.z, al, bb), fmaf(r1.w, al, bb))), 0.f);
    *(float2*)(out + opix) = st;
}

// ---------------------------------------------------------------------------
extern "C" void kernel_launch(void* const* d_in, const int* in_sizes, int n_in,
                              void* d_out, int out_size, void* d_ws, size_t ws_size,
                              hipStream_t stream)
{
    const float* x     = (const float*)d_in[0];
    const float* w_off = (const float*)d_in[1];
    const float* b_off = (const float*)d_in[2];
    const float* w_def = (const float*)d_in[3];
    const float* b_def = (const float*)d_in[4];
    const float* gamma = (const float*)d_in[5];
    const float* beta  = (const float*)d_in[6];
    const float* fc1_w = (const float*)d_in[7];
    const float* fc1_b = (const float*)d_in[8];
    const float* fc2_w = (const float*)d_in[9];
    const float* fc2_b = (const float*)d_in[10];
    float* out = (float*)d_out;

    float* ws   = (float*)d_ws;
    float* offs   = ws;                          // 2,654,208 floats
    float* yb     = offs + 2654208;              // 9,437,184 floats
    float* xt     = yb + 9437184;                // 4,718,592 floats (NHWC x)
    float* wt_def = xt + 4718592;                // 18,432
    float* wt_off = wt_def + 18432;              // 5,760
    float* stats  = wt_off + 5760;               // 1,024
    float* sum_bc   = stats;
    float* sumsq_bc = stats + 256;
    float* alpha    = stats + 512;
    float* bbias    = stats + 768;

    k_pre     <<<dim3(NPIX_ / 256 + 97), dim3(256), 0, stream>>>(
                  x, w_def, w_off, xt, wt_def, wt_off, stats);
    k_conv_off<<<dim3(NPIX_ / 128), dim3(128), 0, stream>>>(xt, wt_off, b_off, offs);
    k_deform  <<<dim3(NPIX_ / 128), dim3(256), 0, stream>>>(xt, offs, wt_def, b_def, yb);
    k_stats   <<<dim3(NPIX_ * 64 / 1024), dim3(256), 0, stream>>>(yb, sum_bc, sumsq_bc);
    k_se      <<<dim3(1), dim3(256), 0, stream>>>(sum_bc, sumsq_bc, gamma, beta,
                                                  fc1_w, fc1_b, fc2_w, fc2_b, alpha, bbias);
    k_finish  <<<dim3(B_ * COUT_ * 96 * 96 / 512), dim3(256), 0, stream>>>(yb, alpha, bbias, out);
}

// Round 8
// 272.358 us; speedup vs baseline: 3.4084x; 1.2054x over previous
//
#include <hip/hip_runtime.h>
#include <math.h>

#define B_    4
#define CIN_  32
#define COUT_ 64
#define H_    192
#define W_    192
#define HW_   (H_ * W_)        // 36864
#define NPIX_ (B_ * HW_)       // 147456
#define EPS_  1e-5f

// XCD-aware swizzle: grid 1152 = 8 XCDs * 144. Round-robin blockIdx->XCD
// gives XCD k a contiguous half-image-plane (2.36 MB xt + 1.33 MB offs
// < 4 MB per-XCD L2). Proven R7: FETCH 300 MB -> 15.5 MB.
static __device__ __forceinline__ int swz1152(int blk) {
    return ((blk & 7) * 144) + (blk >> 3);
}

// ---------------------------------------------------------------------------
// Kernel 0: fused prep. Blocks [0,576): transpose x (NCHW) -> xt (NHWC).
// Blocks [576,673): weight transposes + stats zeroing.
// ---------------------------------------------------------------------------
__global__ __launch_bounds__(256) void k_pre(
    const float* __restrict__ x, const float* __restrict__ w_def,
    const float* __restrict__ w_off, float* __restrict__ xt,
    float* __restrict__ wt_def, float* __restrict__ wt_off,
    float* __restrict__ stats)
{
    if (blockIdx.x < NPIX_ / 256) {
        const int pid = blockIdx.x * 256 + threadIdx.x;
        const int b   = pid / HW_;
        const int rem = pid - b * HW_;
        const float* xb = x + (size_t)b * CIN_ * HW_ + rem;
        float4 v[8];
#pragma unroll
        for (int j = 0; j < 8; ++j) {
            v[j].x = xb[(j * 4 + 0) * HW_];
            v[j].y = xb[(j * 4 + 1) * HW_];
            v[j].z = xb[(j * 4 + 2) * HW_];
            v[j].w = xb[(j * 4 + 3) * HW_];
        }
        float4* dst = (float4*)(xt + (size_t)pid * 32);
#pragma unroll
        for (int j = 0; j < 8; ++j) dst[j] = v[j];
    } else {
        const int i = (blockIdx.x - NPIX_ / 256) * 256 + threadIdx.x;
        if (i < 18432) {                       // wt_def[kk][c][o64]
            const int o  = i & 63;
            const int c  = (i >> 6) & 31;
            const int kk = i >> 11;
            wt_def[i] = w_def[(o * 32 + c) * 9 + kk];
        } else if (i < 18432 + 5760) {         // wt_off[kk][c][o20]
            const int e  = i - 18432;
            const int o  = e % 20;
            const int t  = e / 20;
            const int c  = t & 31;
            const int kk = t >> 5;
            wt_off[e] = (o < 18) ? w_off[(o * 32 + c) * 9 + kk] : 0.f;
        } else if (i < 18432 + 5760 + 512) {
            stats[i - 18432 - 5760] = 0.f;     // sum_bc + sumsq_bc
        }
    }
}

// ---------------------------------------------------------------------------
// Kernel 1: offsets conv (32 -> 18 ch), NHWC input, serial 8-ch chunks,
// XCD-swizzled blocks. (Unchanged from R7.)
// ---------------------------------------------------------------------------
__global__ __launch_bounds__(128, 4) void k_conv_off(
    const float* __restrict__ xt, const float* __restrict__ wt,
    const float* __restrict__ b_off, float* __restrict__ offs)
{
    const int pid = swz1152(blockIdx.x) * 128 + threadIdx.x;
    const int b   = pid / HW_;
    const int rem = pid - b * HW_;
    const int h   = rem / W_;
    const int w   = rem - h * W_;
    const float* xb = xt + (size_t)b * HW_ * 32;

    float acc[20];
#pragma unroll
    for (int o = 0; o < 20; ++o) acc[o] = 0.f;

#pragma unroll 1
    for (int kk = 0; kk < 9; ++kk) {
        const int yy = h + kk / 3 - 1;
        const int sx = w + kk % 3 - 1;
        const bool ok = (yy >= 0) & (yy < H_) & (sx >= 0) & (sx < W_);
        const int cy = min(max(yy, 0), H_ - 1);
        const int cx = min(max(sx, 0), W_ - 1);
        const float g = ok ? 1.f : 0.f;
        const float* cp = xb + (cy * W_ + cx) * 32;

#pragma unroll 1
        for (int c8 = 0; c8 < 4; ++c8) {
            const float4 x0 = *(const float4*)(cp + c8 * 8);
            const float4 x1 = *(const float4*)(cp + c8 * 8 + 4);
            float vs[8] = {x0.x * g, x0.y * g, x0.z * g, x0.w * g,
                           x1.x * g, x1.y * g, x1.z * g, x1.w * g};
#pragma unroll
            for (int e = 0; e < 8; ++e) {
                const float4* wr = (const float4*)(wt + (kk * 32 + c8 * 8 + e) * 20);
                const float a = vs[e];
#pragma unroll
                for (int q = 0; q < 5; ++q) {
                    float4 wv = wr[q];
                    acc[q * 4 + 0] += a * wv.x;
                    acc[q * 4 + 1] += a * wv.y;
                    acc[q * 4 + 2] += a * wv.z;
                    acc[q * 4 + 3] += a * wv.w;
                }
            }
        }
    }

#pragma unroll
    for (int o = 0; o < 18; ++o)
        offs[(b * 18 + o) * HW_ + rem] = acc[o] + b_off[o];
}

// ---------------------------------------------------------------------------
// Kernel 2: deformable conv + fused BN statistics.
// 128-thr blocks (2 waves), one pixel per thread, FULL acc[64] per thread
// (gathers loaded once — no half-wave duplication -> TCP demand halves).
// Serial 8-ch chunks; weights via uniform s_load; XCD swizzle; next-kk
// offsets preloaded. Epilogue: per-wave butterfly channel sums ->
// 2 atomics/lane into sum_bc/sumsq_bc (replaces k_stats).
// launch_bounds(128,2): 256-VGPR cap, est. need ~130 -> no spill.
// ---------------------------------------------------------------------------
__global__ __launch_bounds__(128, 2) void k_deform(
    const float* __restrict__ xt, const float* __restrict__ offs,
    const float* __restrict__ wt, const float* __restrict__ b_def,
    float* __restrict__ y, float* __restrict__ sum_bc,
    float* __restrict__ sumsq_bc)
{
    const int tid  = threadIdx.x;
    const int lane = tid & 63;
    const int pid  = swz1152(blockIdx.x) * 128 + tid;
    const int b    = pid / HW_;
    const int rem  = pid - b * HW_;
    const int h    = rem / W_;
    const int w    = rem - h * W_;
    const float* xb = xt + (size_t)b * HW_ * 32;
    const float* ob = offs + b * 18 * HW_ + rem;

    float acc[64];
#pragma unroll
    for (int o = 0; o < 64; ++o) acc[o] = 0.f;

    float dy = ob[0];
    float dx = ob[HW_];

#pragma unroll 1
    for (int kk = 0; kk < 9; ++kk) {
        float ndy = 0.f, ndx = 0.f;
        if (kk < 8) {                       // preload next kk's offsets early
            ndy = ob[(2 * kk + 2) * HW_];
            ndx = ob[(2 * kk + 3) * HW_];
        }
        const float py = (float)(h + kk / 3 - 1) + dy;
        const float px = (float)(w + kk % 3 - 1) + dx;
        const float y0f = floorf(py), x0f = floorf(px);
        const float wy = py - y0f, wx = px - x0f;
        const int iy0 = (int)y0f, ix0 = (int)x0f;
        const int iy1 = iy0 + 1,  ix1 = ix0 + 1;
        const float vy0 = (iy0 >= 0 && iy0 < H_) ? 1.f : 0.f;
        const float vy1 = (iy1 >= 0 && iy1 < H_) ? 1.f : 0.f;
        const float vx0 = (ix0 >= 0 && ix0 < W_) ? 1.f : 0.f;
        const float vx1 = (ix1 >= 0 && ix1 < W_) ? 1.f : 0.f;
        const float w00 = (1.f - wy) * (1.f - wx) * vy0 * vx0;
        const float w01 = (1.f - wy) * wx * vy0 * vx1;
        const float w10 = wy * (1.f - wx) * vy1 * vx0;
        const float w11 = wy * wx * vy1 * vx1;
        const int cy0 = min(max(iy0, 0), H_ - 1), cy1 = min(max(iy1, 0), H_ - 1);
        const int cx0 = min(max(ix0, 0), W_ - 1), cx1 = min(max(ix1, 0), W_ - 1);
        const int o00 = (cy0 * W_ + cx0) * 32, o01 = (cy0 * W_ + cx1) * 32;
        const int o10 = (cy1 * W_ + cx0) * 32, o11 = (cy1 * W_ + cx1) * 32;

#pragma unroll 1
        for (int c8 = 0; c8 < 4; ++c8) {
            const int co = c8 * 8;
            const float4 a0 = *(const float4*)(xb + o00 + co);
            const float4 b0 = *(const float4*)(xb + o01 + co);
            const float4 c0 = *(const float4*)(xb + o10 + co);
            const float4 d0 = *(const float4*)(xb + o11 + co);
            const float4 a1 = *(const float4*)(xb + o00 + co + 4);
            const float4 b1 = *(const float4*)(xb + o01 + co + 4);
            const float4 c1 = *(const float4*)(xb + o10 + co + 4);
            const float4 d1 = *(const float4*)(xb + o11 + co + 4);
            float v[8];
            v[0] = w00 * a0.x + w01 * b0.x + w10 * c0.x + w11 * d0.x;
            v[1] = w00 * a0.y + w01 * b0.y + w10 * c0.y + w11 * d0.y;
            v[2] = w00 * a0.z + w01 * b0.z + w10 * c0.z + w11 * d0.z;
            v[3] = w00 * a0.w + w01 * b0.w + w10 * c0.w + w11 * d0.w;
            v[4] = w00 * a1.x + w01 * b1.x + w10 * c1.x + w11 * d1.x;
            v[5] = w00 * a1.y + w01 * b1.y + w10 * c1.y + w11 * d1.y;
            v[6] = w00 * a1.z + w01 * b1.z + w10 * c1.z + w11 * d1.z;
            v[7] = w00 * a1.w + w01 * b1.w + w10 * c1.w + w11 * d1.w;
#pragma unroll
            for (int e = 0; e < 8; ++e) {
                const float vc = v[e];
                const float4* wr = (const float4*)(wt + ((kk * 32 + co + e) << 6));
#pragma unroll
                for (int q = 0; q < 16; ++q) {      // all 64 outputs
                    float4 wv = wr[q];
                    acc[q * 4 + 0] += vc * wv.x;
                    acc[q * 4 + 1] += vc * wv.y;
                    acc[q * 4 + 2] += vc * wv.z;
                    acc[q * 4 + 3] += vc * wv.w;
                }
            }
        }
        dy = ndy; dx = ndx;
    }

    // bias + store
    float* yp = y + (size_t)b * COUT_ * HW_ + rem;
#pragma unroll
    for (int o = 0; o < 64; ++o) {
        acc[o] += b_def[o];
        yp[o * HW_] = acc[o];
    }

    // fused BN stats: per-wave channel sums via butterfly; lane o ends up
    // holding channel o's (sum, sumsq) for this wave's 64 pixels.
    // b is wave-uniform (64 consecutive pixels in one image row).
    float ls = 0.f, lq = 0.f;
#pragma unroll
    for (int o = 0; o < 64; ++o) {
        float t = acc[o];
        float u = t * t;
#pragma unroll
        for (int s = 32; s; s >>= 1) {
            t += __shfl_xor(t, s, 64);
            u += __shfl_xor(u, s, 64);
        }
        if (lane == o) { ls = t; lq = u; }
    }
    atomicAdd(&sum_bc[b * 64 + lane], ls);
    atomicAdd(&sumsq_bc[b * 64 + lane], lq);
}

// ---------------------------------------------------------------------------
// Kernel 3: fused SE-MLP + affine(BN*SE) + ReLU + 2x2 maxpool.
// Each block redundantly computes the 256-entry (alpha,bbias) affine from
// sum_bc/sumsq_bc in LDS (cheap), then pools its 512 outputs.
// ---------------------------------------------------------------------------
__global__ __launch_bounds__(256) void k_finish(
    const float* __restrict__ y,
    const float* __restrict__ sum_bc, const float* __restrict__ sumsq_bc,
    const float* __restrict__ gamma, const float* __restrict__ beta,
    const float* __restrict__ fc1_w, const float* __restrict__ fc1_b,
    const float* __restrict__ fc2_w, const float* __restrict__ fc2_b,
    float* __restrict__ out)
{
    __shared__ float sal[256], sbb[256], sin_[256];
    const int tid = threadIdx.x;
    {
        const int b = tid >> 6, c = tid & 63;
        float ch_s = 0.f, ch_q = 0.f;
#pragma unroll
        for (int bb = 0; bb < 4; ++bb) {
            ch_s += sum_bc[bb * 64 + c];
            ch_q += sumsq_bc[bb * 64 + c];
        }
        const float invN = 1.f / (float)(B_ * HW_);
        const float mean = ch_s * invN;
        const float var  = ch_q * invN - mean * mean;
        const float a    = gamma[c] * rsqrtf(var + EPS_);
        const float bi   = beta[c] - mean * a;
        sin_[tid] = a * (sum_bc[tid] * (1.f / (float)HW_)) + bi;
        __syncthreads();
        float hv[4];
#pragma unroll
        for (int j = 0; j < 4; ++j) {
            float hs = fc1_b[j];
            for (int cc = 0; cc < 64; ++cc)
                hs += sin_[b * 64 + cc] * fc1_w[j * 64 + cc];
            hv[j] = fmaxf(hs, 0.f);
        }
        float o = fc2_b[c];
#pragma unroll
        for (int j = 0; j < 4; ++j) o += hv[j] * fc2_w[c * 4 + j];
        const float s = 1.f / (1.f + expf(-o));
        sal[tid] = a * s;
        sbb[tid] = bi * s;
    }
    __syncthreads();

    const int t    = blockIdx.x * 256 + tid;
    const int opix = t * 2;
    const int bc   = opix / (96 * 96);
    const int rem  = opix - bc * (96 * 96);
    const int oh   = rem / 96, ow = rem - oh * 96;   // ow even
    const float al = sal[bc], bb = sbb[bc];
    const float* yp = y + (size_t)bc * HW_ + (2 * oh) * W_ + 2 * ow;
    const float4 r0 = *(const float4*)yp;
    const float4 r1 = *(const float4*)(yp + W_);
    float2 st;
    st.x = fmaxf(fmaxf(fmaxf(fmaf(r0.x, al, bb), fmaf(r0.y, al, bb)),
                       fmaxf(fmaf(r1.x, al, bb), fmaf(r1.y, al, bb))), 0.f);
    st.y = fmaxf(fmaxf(fmaxf(fmaf(r0.z, al, bb), fmaf(r0.w, al, bb)),
                       fmaxf(fmaf(r1.z, al, bb), fmaf(r1.w, al, bb))), 0.f);
    *(float2*)(out + opix) = st;
}

// ---------------------------------------------------------------------------
extern "C" void kernel_launch(void* const* d_in, const int* in_sizes, int n_in,
                              void* d_out, int out_size, void* d_ws, size_t ws_size,
                              hipStream_t stream)
{
    const float* x     = (const float*)d_in[0];
    const float* w_off = (const float*)d_in[1];
    const float* b_off = (const float*)d_in[2];
    const float* w_def = (const float*)d_in[3];
    const float* b_def = (const float*)d_in[4];
    const float* gamma = (const float*)d_in[5];
    const float* beta  = (const float*)d_in[6];
    const float* fc1_w = (const float*)d_in[7];
    const float* fc1_b = (const float*)d_in[8];
    const float* fc2_w = (const float*)d_in[9];
    const float* fc2_b = (const float*)d_in[10];
    float* out = (float*)d_out;

    float* ws   = (float*)d_ws;
    float* offs   = ws;                          // 2,654,208 floats
    float* yb     = offs + 2654208;              // 9,437,184 floats
    float* xt     = yb + 9437184;                // 4,718,592 floats (NHWC x)
    float* wt_def = xt + 4718592;                // 18,432
    float* wt_off = wt_def + 18432;              // 5,760
    float* stats  = wt_off + 5760;               // 1,024
    float* sum_bc   = stats;
    float* sumsq_bc = stats + 256;

    k_pre     <<<dim3(NPIX_ / 256 + 97), dim3(256), 0, stream>>>(
                  x, w_def, w_off, xt, wt_def, wt_off, stats);
    k_conv_off<<<dim3(NPIX_ / 128), dim3(128), 0, stream>>>(xt, wt_off, b_off, offs);
    k_deform  <<<dim3(NPIX_ / 128), dim3(128), 0, stream>>>(xt, offs, wt_def, b_def,
                                                            yb, sum_bc, sumsq_bc);
    k_finish  <<<dim3(B_ * COUT_ * 96 * 96 / 512), dim3(256), 0, stream>>>(
                  yb, sum_bc, sumsq_bc, gamma, beta,
                  fc1_w, fc1_b, fc2_w, fc2_b, out);
}

// Round 9
// 248.945 us; speedup vs baseline: 3.7290x; 1.0940x over previous
//
#include <hip/hip_runtime.h>
#include <math.h>

#define B_    4
#define CIN_  32
#define COUT_ 64
#define H_    192
#define W_    192
#define HW_   (H_ * W_)        // 36864
#define NPIX_ (B_ * HW_)       // 147456
#define EPS_  1e-5f

// XCD-aware swizzle: grid 1152 = 8 XCDs * 144. Proven R7: FETCH 300->15.5 MB.
static __device__ __forceinline__ int swz1152(int blk) {
    return ((blk & 7) * 144) + (blk >> 3);
}

struct Cr { int o00, o01, o10, o11; float w00, w01, w10, w11; };

// ---------------------------------------------------------------------------
// Kernel 0: fused prep. Blocks [0,576): transpose x (NCHW) -> xt (NHWC).
// Blocks [576,673): weight transposes + stats zeroing.
// ---------------------------------------------------------------------------
__global__ __launch_bounds__(256) void k_pre(
    const float* __restrict__ x, const float* __restrict__ w_def,
    const float* __restrict__ w_off, float* __restrict__ xt,
    float* __restrict__ wt_def, float* __restrict__ wt_off,
    float* __restrict__ stats)
{
    if (blockIdx.x < NPIX_ / 256) {
        const int pid = blockIdx.x * 256 + threadIdx.x;
        const int b   = pid / HW_;
        const int rem = pid - b * HW_;
        const float* xb = x + (size_t)b * CIN_ * HW_ + rem;
        float4 v[8];
#pragma unroll
        for (int j = 0; j < 8; ++j) {
            v[j].x = xb[(j * 4 + 0) * HW_];
            v[j].y = xb[(j * 4 + 1) * HW_];
            v[j].z = xb[(j * 4 + 2) * HW_];
            v[j].w = xb[(j * 4 + 3) * HW_];
        }
        float4* dst = (float4*)(xt + (size_t)pid * 32);
#pragma unroll
        for (int j = 0; j < 8; ++j) dst[j] = v[j];
    } else {
        const int i = (blockIdx.x - NPIX_ / 256) * 256 + threadIdx.x;
        if (i < 18432) {                       // wt_def[kk][c][o64]
            const int o  = i & 63;
            const int c  = (i >> 6) & 31;
            const int kk = i >> 11;
            wt_def[i] = w_def[(o * 32 + c) * 9 + kk];
        } else if (i < 18432 + 5760) {         // wt_off[kk][c][o20]
            const int e  = i - 18432;
            const int o  = e % 20;
            const int t  = e / 20;
            const int c  = t & 31;
            const int kk = t >> 5;
            wt_off[e] = (o < 18) ? w_off[(o * 32 + c) * 9 + kk] : 0.f;
        } else if (i < 18432 + 5760 + 512) {
            stats[i - 18432 - 5760] = 0.f;     // sum_bc + sumsq_bc
        }
    }
}

// ---------------------------------------------------------------------------
// Kernel 1: offsets conv (32 -> 18 ch). 512 threads per 128 px: thread
// (px, grp) accumulates partial acc[20] over channels [8grp,8grp+8),
// then one-barrier LDS reduce (pad 21 -> conflict-free). 9216 waves.
// ---------------------------------------------------------------------------
__global__ __launch_bounds__(512, 6) void k_conv_off(
    const float* __restrict__ xt, const float* __restrict__ wt,
    const float* __restrict__ b_off, float* __restrict__ offs)
{
    __shared__ float rlds[4 * 128 * 21];       // [grp][px][21]
    const int tid = threadIdx.x;
    const int px  = tid & 127;
    const int grp = __builtin_amdgcn_readfirstlane(tid >> 7);
    const int pid = swz1152(blockIdx.x) * 128 + px;
    const int b   = pid / HW_;
    const int rem = pid - b * HW_;
    const int h   = rem / W_;
    const int w   = rem - h * W_;
    const float* xg = xt + (size_t)b * HW_ * 32 + grp * 8;

    float acc[20];
#pragma unroll
    for (int o = 0; o < 20; ++o) acc[o] = 0.f;

    auto tapoff = [&](int kk, float& g) -> int {
        const int yy = h + kk / 3 - 1;
        const int sx = w + kk % 3 - 1;
        const bool ok = (yy >= 0) & (yy < H_) & (sx >= 0) & (sx < W_);
        g = ok ? 1.f : 0.f;
        const int cy = min(max(yy, 0), H_ - 1);
        const int cx = min(max(sx, 0), W_ - 1);
        return (cy * W_ + cx) * 32;
    };

    float g; int off = tapoff(0, g);
    float4 x0 = *(const float4*)(xg + off);
    float4 x1 = *(const float4*)(xg + off + 4);

#pragma unroll 1
    for (int kk = 0; kk < 9; ++kk) {
        float ng = 0.f; float4 nx0, nx1;
        if (kk < 8) {                           // prefetch next tap
            const int noff = tapoff(kk + 1, ng);
            nx0 = *(const float4*)(xg + noff);
            nx1 = *(const float4*)(xg + noff + 4);
        }
        const float vs[8] = {x0.x * g, x0.y * g, x0.z * g, x0.w * g,
                             x1.x * g, x1.y * g, x1.z * g, x1.w * g};
#pragma unroll
        for (int e = 0; e < 8; ++e) {
            const float4* wr = (const float4*)(wt + (kk * 32 + grp * 8 + e) * 20);
            const float a = vs[e];
#pragma unroll
            for (int q = 0; q < 5; ++q) {
                float4 wv = wr[q];
                acc[q * 4 + 0] += a * wv.x;
                acc[q * 4 + 1] += a * wv.y;
                acc[q * 4 + 2] += a * wv.z;
                acc[q * 4 + 3] += a * wv.w;
            }
        }
        x0 = nx0; x1 = nx1; g = ng;
    }

    float* rp = &rlds[(grp * 128 + px) * 21];
#pragma unroll
    for (int o = 0; o < 20; ++o) rp[o] = acc[o];
    __syncthreads();

#pragma unroll
    for (int j = 0; j < 5; ++j) {
        const int o = grp * 5 + j;
        if (o < 18) {
            const float s = rlds[(0 * 128 + px) * 21 + o]
                          + rlds[(1 * 128 + px) * 21 + o]
                          + rlds[(2 * 128 + px) * 21 + o]
                          + rlds[(3 * 128 + px) * 21 + o];
            offs[(b * 18 + o) * HW_ + rem] = s + b_off[o];
        }
    }
}

// ---------------------------------------------------------------------------
// Kernel 2: deformable conv + fused BN stats. 512 threads per 128 px.
// Phase 1 (per kk): thread (px,grp) gathers channels [8grp,+8) for its
// pixel's 4 bilinear corners (no duplication), computes v[8], stores to
// LDS v[c][px] (transposed, stride-1, conflict-free). Next kk's corner
// loads issued before phase 2 (in flight across the barrier).
// Phase 2: thread computes 16 outputs [16grp,+16) from all 32 LDS
// channels; weights via uniform s_load. Epilogue: bias+store+wave
// butterfly stats. 9216 waves; ~80 VGPR under 85 cap.
// ---------------------------------------------------------------------------
__global__ __launch_bounds__(512, 6) void k_deform(
    const float* __restrict__ xt, const float* __restrict__ offs,
    const float* __restrict__ wt, const float* __restrict__ b_def,
    float* __restrict__ y, float* __restrict__ sum_bc,
    float* __restrict__ sumsq_bc)
{
    __shared__ float vlds[32 * 128];           // [c][px], 16 KB
    const int tid  = threadIdx.x;
    const int px   = tid & 127;
    const int grp  = __builtin_amdgcn_readfirstlane(tid >> 7);
    const int lane = tid & 63;
    const int pid  = swz1152(blockIdx.x) * 128 + px;
    const int b    = pid / HW_;
    const int rem  = pid - b * HW_;
    const int h    = rem / W_;
    const int w    = rem - h * W_;
    const float* xg = xt + (size_t)b * HW_ * 32 + grp * 8;
    const float* ob = offs + b * 18 * HW_ + rem;

    float acc[16];
#pragma unroll
    for (int q = 0; q < 16; ++q) acc[q] = 0.f;

    auto mk = [&](int kk, float dy, float dx) -> Cr {
        const float py = (float)(h + kk / 3 - 1) + dy;
        const float qx = (float)(w + kk % 3 - 1) + dx;
        const float y0f = floorf(py), x0f = floorf(qx);
        const float wy = py - y0f, wx = qx - x0f;
        const int iy0 = (int)y0f, ix0 = (int)x0f;
        const int iy1 = iy0 + 1,  ix1 = ix0 + 1;
        const float vy0 = (iy0 >= 0 && iy0 < H_) ? 1.f : 0.f;
        const float vy1 = (iy1 >= 0 && iy1 < H_) ? 1.f : 0.f;
        const float vx0 = (ix0 >= 0 && ix0 < W_) ? 1.f : 0.f;
        const float vx1 = (ix1 >= 0 && ix1 < W_) ? 1.f : 0.f;
        Cr c;
        c.w00 = (1.f - wy) * (1.f - wx) * vy0 * vx0;
        c.w01 = (1.f - wy) * wx * vy0 * vx1;
        c.w10 = wy * (1.f - wx) * vy1 * vx0;
        c.w11 = wy * wx * vy1 * vx1;
        const int cy0 = min(max(iy0, 0), H_ - 1), cy1 = min(max(iy1, 0), H_ - 1);
        const int cx0 = min(max(ix0, 0), W_ - 1), cx1 = min(max(ix1, 0), W_ - 1);
        c.o00 = (cy0 * W_ + cx0) * 32; c.o01 = (cy0 * W_ + cx1) * 32;
        c.o10 = (cy1 * W_ + cx0) * 32; c.o11 = (cy1 * W_ + cx1) * 32;
        return c;
    };

    // software pipeline: corner loads for kk in regs, offsets for kk+1 loaded
    float dy = ob[0], dx = ob[HW_];
    Cr cur = mk(0, dy, dx);
    float4 A0 = *(const float4*)(xg + cur.o00), A1 = *(const float4*)(xg + cur.o00 + 4);
    float4 B0 = *(const float4*)(xg + cur.o01), B1 = *(const float4*)(xg + cur.o01 + 4);
    float4 C0 = *(const float4*)(xg + cur.o10), C1 = *(const float4*)(xg + cur.o10 + 4);
    float4 D0 = *(const float4*)(xg + cur.o11), D1 = *(const float4*)(xg + cur.o11 + 4);
    float ndy = ob[2 * HW_], ndx = ob[3 * HW_];

#pragma unroll 1
    for (int kk = 0; kk < 9; ++kk) {
        __syncthreads();                       // previous phase-2 reads done
        float v[8];
        v[0] = cur.w00 * A0.x + cur.w01 * B0.x + cur.w10 * C0.x + cur.w11 * D0.x;
        v[1] = cur.w00 * A0.y + cur.w01 * B0.y + cur.w10 * C0.y + cur.w11 * D0.y;
        v[2] = cur.w00 * A0.z + cur.w01 * B0.z + cur.w10 * C0.z + cur.w11 * D0.z;
        v[3] = cur.w00 * A0.w + cur.w01 * B0.w + cur.w10 * C0.w + cur.w11 * D0.w;
        v[4] = cur.w00 * A1.x + cur.w01 * B1.x + cur.w10 * C1.x + cur.w11 * D1.x;
        v[5] = cur.w00 * A1.y + cur.w01 * B1.y + cur.w10 * C1.y + cur.w11 * D1.y;
        v[6] = cur.w00 * A1.z + cur.w01 * B1.z + cur.w10 * C1.z + cur.w11 * D1.z;
        v[7] = cur.w00 * A1.w + cur.w01 * B1.w + cur.w10 * C1.w + cur.w11 * D1.w;
#pragma unroll
        for (int j = 0; j < 8; ++j) vlds[(grp * 8 + j) * 128 + px] = v[j];

        if (kk < 8) {                          // issue next kk's gathers now;
            cur = mk(kk + 1, ndy, ndx);        // they fly during phase 2
            A0 = *(const float4*)(xg + cur.o00); A1 = *(const float4*)(xg + cur.o00 + 4);
            B0 = *(const float4*)(xg + cur.o01); B1 = *(const float4*)(xg + cur.o01 + 4);
            C0 = *(const float4*)(xg + cur.o10); C1 = *(const float4*)(xg + cur.o10 + 4);
            D0 = *(const float4*)(xg + cur.o11); D1 = *(const float4*)(xg + cur.o11 + 4);
            if (kk < 7) {
                ndy = ob[(2 * kk + 4) * HW_];
                ndx = ob[(2 * kk + 5) * HW_];
            }
        }
        __syncthreads();                       // v(kk) visible

        const float* wk = wt + (kk << 11) + (grp << 4);   // wt[kk][.][16grp]
#pragma unroll 8
        for (int c = 0; c < 32; ++c) {
            const float vv = vlds[c * 128 + px];
            const float4* wr = (const float4*)(wk + (c << 6));
            const float4 w0 = wr[0], w1 = wr[1], w2 = wr[2], w3 = wr[3];
            acc[ 0] += vv * w0.x; acc[ 1] += vv * w0.y;
            acc[ 2] += vv * w0.z; acc[ 3] += vv * w0.w;
            acc[ 4] += vv * w1.x; acc[ 5] += vv * w1.y;
            acc[ 6] += vv * w1.z; acc[ 7] += vv * w1.w;
            acc[ 8] += vv * w2.x; acc[ 9] += vv * w2.y;
            acc[10] += vv * w2.z; acc[11] += vv * w2.w;
            acc[12] += vv * w3.x; acc[13] += vv * w3.y;
            acc[14] += vv * w3.z; acc[15] += vv * w3.w;
        }
    }

    // bias + store (16 channels for this grp)
    float* yp = y + ((size_t)b * COUT_ + grp * 16) * HW_ + rem;
#pragma unroll
    for (int q = 0; q < 16; ++q) {
        acc[q] += b_def[grp * 16 + q];
        yp[q * HW_] = acc[q];
    }

    // fused BN stats: wave = (64 px, one grp). Butterfly each of the 16
    // channels over 64 px; lane o keeps channel o's (sum, sumsq).
    float ls = 0.f, lq = 0.f;
#pragma unroll
    for (int o = 0; o < 16; ++o) {
        float t = acc[o];
        float u = t * t;
#pragma unroll
        for (int s = 32; s; s >>= 1) {
            t += __shfl_xor(t, s, 64);
            u += __shfl_xor(u, s, 64);
        }
        if (lane == o) { ls = t; lq = u; }
    }
    if (lane < 16) {
        atomicAdd(&sum_bc[b * 64 + grp * 16 + lane], ls);
        atomicAdd(&sumsq_bc[b * 64 + grp * 16 + lane], lq);
    }
}

// ---------------------------------------------------------------------------
// Kernel 3: fused SE-MLP + affine(BN*SE) + ReLU + 2x2 maxpool.
// ---------------------------------------------------------------------------
__global__ __launch_bounds__(256) void k_finish(
    const float* __restrict__ y,
    const float* __restrict__ sum_bc, const float* __restrict__ sumsq_bc,
    const float* __restrict__ gamma, const float* __restrict__ beta,
    const float* __restrict__ fc1_w, const float* __restrict__ fc1_b,
    const float* __restrict__ fc2_w, const float* __restrict__ fc2_b,
    float* __restrict__ out)
{
    __shared__ float sal[256], sbb[256], sin_[256];
    const int tid = threadIdx.x;
    {
        const int b = tid >> 6, c = tid & 63;
        float ch_s = 0.f, ch_q = 0.f;
#pragma unroll
        for (int bb = 0; bb < 4; ++bb) {
            ch_s += sum_bc[bb * 64 + c];
            ch_q += sumsq_bc[bb * 64 + c];
        }
        const float invN = 1.f / (float)(B_ * HW_);
        const float mean = ch_s * invN;
        const float var  = ch_q * invN - mean * mean;
        const float a    = gamma[c] * rsqrtf(var + EPS_);
        const float bi   = beta[c] - mean * a;
        sin_[tid] = a * (sum_bc[tid] * (1.f / (float)HW_)) + bi;
        __syncthreads();
        float hv[4];
#pragma unroll
        for (int j = 0; j < 4; ++j) {
            float hs = fc1_b[j];
            for (int cc = 0; cc < 64; ++cc)
                hs += sin_[b * 64 + cc] * fc1_w[j * 64 + cc];
            hv[j] = fmaxf(hs, 0.f);
        }
        float o = fc2_b[c];
#pragma unroll
        for (int j = 0; j < 4; ++j) o += hv[j] * fc2_w[c * 4 + j];
        const float s = 1.f / (1.f + expf(-o));
        sal[tid] = a * s;
        sbb[tid] = bi * s;
    }
    __syncthreads();

    const int t    = blockIdx.x * 256 + tid;
    const int opix = t * 2;
    const int bc   = opix / (96 * 96);
    const int rem  = opix - bc * (96 * 96);
    const int oh   = rem / 96, ow = rem - oh * 96;   // ow even
    const float al = sal[bc], bb = sbb[bc];
    const float* yp = y + (size_t)bc * HW_ + (2 * oh) * W_ + 2 * ow;
    const float4 r0 = *(const float4*)yp;
    const float4 r1 = *(const float4*)(yp + W_);
    float2 st;
    st.x = fmaxf(fmaxf(fmaxf(fmaf(r0.x, al, bb), fmaf(r0.y, al, bb)),
                       fmaxf(fmaf(r1.x, al, bb), fmaf(r1.y, al, bb))), 0.f);
    st.y = fmaxf(fmaxf(fmaxf(fmaf(r0.z, al, bb), fmaf(r0.w, al, bb)),
                       fmaxf(fmaf(r1.z, al, bb), fmaf(r1.w, al, bb))), 0.f);
    *(float2*)(out + opix) = st;
}

// ---------------------------------------------------------------------------
extern "C" void kernel_launch(void* const* d_in, const int* in_sizes, int n_in,
                              void* d_out, int out_size, void* d_ws, size_t ws_size,
                              hipStream_t stream)
{
    const float* x     = (const float*)d_in[0];
    const float* w_off = (const float*)d_in[1];
    const float* b_off = (const float*)d_in[2];
    const float* w_def = (const float*)d_in[3];
    const float* b_def = (const float*)d_in[4];
    const float* gamma = (const float*)d_in[5];
    const float* beta  = (const float*)d_in[6];
    const float* fc1_w = (const float*)d_in[7];
    const float* fc1_b = (const float*)d_in[8];
    const float* fc2_w = (const float*)d_in[9];
    const float* fc2_b = (const float*)d_in[10];
    float* out = (float*)d_out;

    float* ws   = (float*)d_ws;
    float* offs   = ws;                          // 2,654,208 floats
    float* yb     = offs + 2654208;              // 9,437,184 floats
    float* xt     = yb + 9437184;                // 4,718,592 floats (NHWC x)
    float* wt_def = xt + 4718592;                // 18,432
    float* wt_off = wt_def + 18432;              // 5,760
    float* stats  = wt_off + 5760;               // 1,024
    float* sum_bc   = stats;
    float* sumsq_bc = stats + 256;

    k_pre     <<<dim3(NPIX_ / 256 + 97), dim3(256), 0, stream>>>(
                  x, w_def, w_off, xt, wt_def, wt_off, stats);
    k_conv_off<<<dim3(NPIX_ / 128), dim3(512), 0, stream>>>(xt, wt_off, b_off, offs);
    k_deform  <<<dim3(NPIX_ / 128), dim3(512), 0, stream>>>(xt, offs, wt_def, b_def,
                                                            yb, sum_bc, sumsq_bc);
    k_finish  <<<dim3(B_ * COUT_ * 96 * 96 / 512), dim3(256), 0, stream>>>(
                  yb, sum_bc, sumsq_bc, gamma, beta,
                  fc1_w, fc1_b, fc2_w, fc2_b, out);
}